// Round 1
// baseline (6338.969 us; speedup 1.0000x reference)
//
#include <hip/hip_runtime.h>

#define NN 50000
#define NE 800000
#define NR 8
#define DIN 128
#define DOUT 128
#define NH 8
#define DHD 16

// ---------- helpers ----------
__device__ __forceinline__ unsigned short f2bf(float f) {
  unsigned u = __float_as_uint(f);
  unsigned r = (u + 0x7FFFu + ((u >> 16) & 1u)) >> 16;
  return (unsigned short)r;
}
__device__ __forceinline__ float bf2f(unsigned short b) {
  return __uint_as_float(((unsigned)b) << 16);
}
// monotone float->uint encoding for atomicMax
__device__ __forceinline__ unsigned encf(float x) {
  unsigned ub = __float_as_uint(x);
  return (ub & 0x80000000u) ? ~ub : (ub | 0x80000000u);
}
__device__ __forceinline__ float decf(unsigned u) {
  unsigned b = (u & 0x80000000u) ? (u & 0x7FFFFFFFu) : ~u;
  return __uint_as_float(b);
}
__device__ __forceinline__ void unpack8(uint4 u, float* f) {
  f[0] = __uint_as_float((u.x & 0xFFFFu) << 16);
  f[1] = __uint_as_float(u.x & 0xFFFF0000u);
  f[2] = __uint_as_float((u.y & 0xFFFFu) << 16);
  f[3] = __uint_as_float(u.y & 0xFFFF0000u);
  f[4] = __uint_as_float((u.z & 0xFFFFu) << 16);
  f[5] = __uint_as_float(u.z & 0xFFFF0000u);
  f[6] = __uint_as_float((u.w & 0xFFFFu) << 16);
  f[7] = __uint_as_float(u.w & 0xFFFF0000u);
}

// ---------- kernel 1: z[r,n,o] = h[n,:] @ fc[r,:,o]  (bf16 out) ----------
// 64x64 tile, 256 threads, 4x4 per thread, K-chunks of 16
__global__ __launch_bounds__(256) void gemm_z(
    const float* __restrict__ h, const float* __restrict__ fc,
    unsigned short* __restrict__ z) {
  const int r = blockIdx.z;
  const int n0 = blockIdx.x * 64;
  const int o0 = blockIdx.y * 64;
  const int t = threadIdx.x;
  const int tx = t & 15, ty = t >> 4;
  __shared__ float As[16][64];  // [kk][n]
  __shared__ float Bs[16][64];  // [kk][o]
  float acc[4][4] = {};
  const float* fcr = fc + r * DIN * DOUT;

  for (int k0 = 0; k0 < DIN; k0 += 16) {
    {  // load A: 64 nodes x 16 k, transposed into LDS
      int n = t >> 2;
      int c = (t & 3) * 4;
      int gn = n0 + n;
      float4 v = make_float4(0.f, 0.f, 0.f, 0.f);
      if (gn < NN) v = *(const float4*)&h[gn * DIN + k0 + c];
      As[c + 0][n] = v.x; As[c + 1][n] = v.y;
      As[c + 2][n] = v.z; As[c + 3][n] = v.w;
    }
    {  // load B: 16 k x 64 o
      int kk = t >> 4;
      int o4 = (t & 15) * 4;
      float4 v = *(const float4*)&fcr[(k0 + kk) * DOUT + o0 + o4];
      *(float4*)&Bs[kk][o4] = v;
    }
    __syncthreads();
#pragma unroll
    for (int kk = 0; kk < 16; ++kk) {
      float4 a = *(float4*)&As[kk][ty * 4];
      float4 b = *(float4*)&Bs[kk][tx * 4];
      float av[4] = {a.x, a.y, a.z, a.w};
      float bv[4] = {b.x, b.y, b.z, b.w};
#pragma unroll
      for (int i = 0; i < 4; ++i)
#pragma unroll
        for (int j = 0; j < 4; ++j) acc[i][j] += av[i] * bv[j];
    }
    __syncthreads();
  }
#pragma unroll
  for (int i = 0; i < 4; ++i) {
    int gn = n0 + ty * 4 + i;
    if (gn < NN) {
      ushort4 w;
      w.x = f2bf(acc[i][0]); w.y = f2bf(acc[i][1]);
      w.z = f2bf(acc[i][2]); w.w = f2bf(acc[i][3]);
      *(ushort4*)&z[((size_t)r * NN + gn) * DOUT + o0 + tx * 4] = w;
    }
  }
}

// ---------- kernel 2: per-node attention scores ----------
// s_l[(r*NN+n)*8+h] = sum_d z[r,n,h*16+d]*aw[r,h,d]; s_r with aw[r,h,16+d]
__global__ __launch_bounds__(256) void scores_kernel(
    const unsigned short* __restrict__ z, const float* __restrict__ attn,
    float* __restrict__ s_l, float* __restrict__ s_r) {
  int idx = blockIdx.x * blockDim.x + threadIdx.x;
  if (idx >= NR * NN) return;
  int r = idx / NN;
  int n = idx - r * NN;
  const uint4* zp = (const uint4*)(z + ((size_t)r * NN + n) * DOUT);
  const float* aw = attn + r * NH * 32;
#pragma unroll
  for (int hh = 0; hh < NH; ++hh) {
    float f[16];
    unpack8(zp[2 * hh], f);
    unpack8(zp[2 * hh + 1], f + 8);
    float sl = 0.f, sr = 0.f;
#pragma unroll
    for (int d = 0; d < 16; ++d) {
      sl += f[d] * aw[hh * 32 + d];
      sr += f[d] * aw[hh * 32 + 16 + d];
    }
    s_l[((size_t)r * NN + n) * NH + hh] = sl;
    s_r[((size_t)r * NN + n) * NH + hh] = sr;
  }
}

// ---------- kernel 3: per-(dst,h) running max via encoded atomicMax ----------
__global__ __launch_bounds__(256) void edge_max(
    const int* __restrict__ src, const int* __restrict__ dst,
    const int* __restrict__ et, const float* __restrict__ s_l,
    const float* __restrict__ s_r, unsigned* __restrict__ m_enc) {
  int e = blockIdx.x * blockDim.x + threadIdx.x;
  if (e >= NE) return;
  int s = src[e], d = dst[e], r = et[e];
  const float4* slp = (const float4*)&s_l[((size_t)r * NN + s) * NH];
  const float4* srp = (const float4*)&s_r[((size_t)r * NN + d) * NH];
  float4 a0 = slp[0], a1 = slp[1], b0 = srp[0], b1 = srp[1];
  float ev[8] = {a0.x + b0.x, a0.y + b0.y, a0.z + b0.z, a0.w + b0.w,
                 a1.x + b1.x, a1.y + b1.y, a1.z + b1.z, a1.w + b1.w};
#pragma unroll
  for (int hh = 0; hh < NH; ++hh) {
    float x = ev[hh];
    x = x > 0.f ? x : 0.01f * x;
    atomicMax(&m_enc[d * NH + hh], encf(x));
  }
}

// ---------- kernel 4: exp, denom + weighted scatter-add of z_s ----------
__global__ __launch_bounds__(256) void edge_accum(
    const int* __restrict__ src, const int* __restrict__ dst,
    const int* __restrict__ et, const float* __restrict__ s_l,
    const float* __restrict__ s_r, const unsigned* __restrict__ m_enc,
    const unsigned short* __restrict__ z, float* __restrict__ denom,
    float* __restrict__ out) {
  int e = blockIdx.x * blockDim.x + threadIdx.x;
  if (e >= NE) return;
  int s = src[e], d = dst[e], r = et[e];
  const float4* slp = (const float4*)&s_l[((size_t)r * NN + s) * NH];
  const float4* srp = (const float4*)&s_r[((size_t)r * NN + d) * NH];
  float4 a0 = slp[0], a1 = slp[1], b0 = srp[0], b1 = srp[1];
  float ev[8] = {a0.x + b0.x, a0.y + b0.y, a0.z + b0.z, a0.w + b0.w,
                 a1.x + b1.x, a1.y + b1.y, a1.z + b1.z, a1.w + b1.w};
  float ex[8];
#pragma unroll
  for (int hh = 0; hh < NH; ++hh) {
    float x = ev[hh];
    x = x > 0.f ? x : 0.01f * x;
    float m = decf(m_enc[d * NH + hh]);
    ex[hh] = __expf(x - m);
    unsafeAtomicAdd(&denom[d * NH + hh], ex[hh]);
  }
  const uint4* zp = (const uint4*)(z + ((size_t)r * NN + s) * DOUT);
  float* ob = out + (size_t)d * DOUT;
#pragma unroll
  for (int q = 0; q < 16; ++q) {
    uint4 u = zp[q];
    float f[8];
    unpack8(u, f);
    float exh = ex[q >> 1];
    int base = q * 8;
#pragma unroll
    for (int k = 0; k < 8; ++k) unsafeAtomicAdd(&ob[base + k], exh * f[k]);
  }
}

// ---------- kernel 5: divide by denom ----------
__global__ __launch_bounds__(256) void finalize(
    float* __restrict__ out, const float* __restrict__ denom) {
  int idx = blockIdx.x * blockDim.x + threadIdx.x;
  if (idx >= NN * DOUT) return;
  int n = idx >> 7;
  int hh = (idx >> 4) & 7;
  float den = denom[n * NH + hh];
  out[idx] *= 1.0f / fmaxf(den, 1e-9f);
}

extern "C" void kernel_launch(void* const* d_in, const int* in_sizes, int n_in,
                              void* d_out, int out_size, void* d_ws, size_t ws_size,
                              hipStream_t stream) {
  const float* h = (const float*)d_in[0];
  const float* fc = (const float*)d_in[1];
  const float* attn = (const float*)d_in[2];
  const int* src = (const int*)d_in[3];
  const int* dst = (const int*)d_in[4];
  const int* et = (const int*)d_in[5];
  float* out = (float*)d_out;

  // workspace layout
  char* wsb = (char*)d_ws;
  unsigned short* z = (unsigned short*)wsb;                    // R*N*128 bf16 = 102.4 MB
  size_t off = (size_t)NR * NN * DOUT * sizeof(unsigned short);
  float* s_l = (float*)(wsb + off); off += (size_t)NR * NN * NH * sizeof(float);   // 12.8 MB
  float* s_r = (float*)(wsb + off); off += (size_t)NR * NN * NH * sizeof(float);   // 12.8 MB
  unsigned* m_enc = (unsigned*)(wsb + off); off += (size_t)NN * NH * sizeof(unsigned); // 1.6 MB
  float* denom = (float*)(wsb + off); off += (size_t)NN * NH * sizeof(float);          // 1.6 MB

  // init accumulators (ws/out are poisoned before every launch)
  hipMemsetAsync(d_out, 0, (size_t)NN * DOUT * sizeof(float), stream);
  hipMemsetAsync(m_enc, 0, (size_t)NN * NH * sizeof(unsigned), stream);
  hipMemsetAsync(denom, 0, (size_t)NN * NH * sizeof(float), stream);

  dim3 ggrid((NN + 63) / 64, 2, NR);
  gemm_z<<<ggrid, 256, 0, stream>>>(h, fc, z);

  scores_kernel<<<(NR * NN + 255) / 256, 256, 0, stream>>>(z, attn, s_l, s_r);

  edge_max<<<(NE + 255) / 256, 256, 0, stream>>>(src, dst, et, s_l, s_r, m_enc);

  edge_accum<<<(NE + 255) / 256, 256, 0, stream>>>(src, dst, et, s_l, s_r,
                                                   m_enc, z, denom, out);

  finalize<<<(NN * DOUT + 255) / 256, 256, 0, stream>>>(out, denom);
}

// Round 2
// 564.894 us; speedup vs baseline: 11.2215x; 11.2215x over previous
//
#include <hip/hip_runtime.h>

#define NN 50000
#define NE 800000
#define NR 8
#define DIN 128
#define DOUT 128
#define NH 8
#define DHD 16

// ---------- helpers ----------
__device__ __forceinline__ unsigned short f2bf(float f) {
  unsigned u = __float_as_uint(f);
  unsigned r = (u + 0x7FFFu + ((u >> 16) & 1u)) >> 16;
  return (unsigned short)r;
}
__device__ __forceinline__ float bf2f(unsigned short b) {
  return __uint_as_float(((unsigned)b) << 16);
}
__device__ __forceinline__ void unpack8(uint4 u, float* f) {
  f[0] = __uint_as_float((u.x & 0xFFFFu) << 16);
  f[1] = __uint_as_float(u.x & 0xFFFF0000u);
  f[2] = __uint_as_float((u.y & 0xFFFFu) << 16);
  f[3] = __uint_as_float(u.y & 0xFFFF0000u);
  f[4] = __uint_as_float((u.z & 0xFFFFu) << 16);
  f[5] = __uint_as_float(u.z & 0xFFFF0000u);
  f[6] = __uint_as_float((u.w & 0xFFFFu) << 16);
  f[7] = __uint_as_float(u.w & 0xFFFF0000u);
}

// ---------- kernel 1: z[r,n,o] = h[n,:] @ fc[r,:,o]  (bf16 out) ----------
__global__ __launch_bounds__(256) void gemm_z(
    const float* __restrict__ h, const float* __restrict__ fc,
    unsigned short* __restrict__ z) {
  const int r = blockIdx.z;
  const int n0 = blockIdx.x * 64;
  const int o0 = blockIdx.y * 64;
  const int t = threadIdx.x;
  const int tx = t & 15, ty = t >> 4;
  __shared__ float As[16][64];
  __shared__ float Bs[16][64];
  float acc[4][4] = {};
  const float* fcr = fc + r * DIN * DOUT;

  for (int k0 = 0; k0 < DIN; k0 += 16) {
    {
      int n = t >> 2;
      int c = (t & 3) * 4;
      int gn = n0 + n;
      float4 v = make_float4(0.f, 0.f, 0.f, 0.f);
      if (gn < NN) v = *(const float4*)&h[gn * DIN + k0 + c];
      As[c + 0][n] = v.x; As[c + 1][n] = v.y;
      As[c + 2][n] = v.z; As[c + 3][n] = v.w;
    }
    {
      int kk = t >> 4;
      int o4 = (t & 15) * 4;
      float4 v = *(const float4*)&fcr[(k0 + kk) * DOUT + o0 + o4];
      *(float4*)&Bs[kk][o4] = v;
    }
    __syncthreads();
#pragma unroll
    for (int kk = 0; kk < 16; ++kk) {
      float4 a = *(float4*)&As[kk][ty * 4];
      float4 b = *(float4*)&Bs[kk][tx * 4];
      float av[4] = {a.x, a.y, a.z, a.w};
      float bv[4] = {b.x, b.y, b.z, b.w};
#pragma unroll
      for (int i = 0; i < 4; ++i)
#pragma unroll
        for (int j = 0; j < 4; ++j) acc[i][j] += av[i] * bv[j];
    }
    __syncthreads();
  }
#pragma unroll
  for (int i = 0; i < 4; ++i) {
    int gn = n0 + ty * 4 + i;
    if (gn < NN) {
      ushort4 w;
      w.x = f2bf(acc[i][0]); w.y = f2bf(acc[i][1]);
      w.z = f2bf(acc[i][2]); w.w = f2bf(acc[i][3]);
      *(ushort4*)&z[((size_t)r * NN + gn) * DOUT + o0 + tx * 4] = w;
    }
  }
}

// ---------- kernel 2: per-node attention scores ----------
__global__ __launch_bounds__(256) void scores_kernel(
    const unsigned short* __restrict__ z, const float* __restrict__ attn,
    float* __restrict__ s_l, float* __restrict__ s_r) {
  int idx = blockIdx.x * blockDim.x + threadIdx.x;
  if (idx >= NR * NN) return;
  int r = idx / NN;
  int n = idx - r * NN;
  const uint4* zp = (const uint4*)(z + ((size_t)r * NN + n) * DOUT);
  const float* aw = attn + r * NH * 32;
#pragma unroll
  for (int hh = 0; hh < NH; ++hh) {
    float f[16];
    unpack8(zp[2 * hh], f);
    unpack8(zp[2 * hh + 1], f + 8);
    float sl = 0.f, sr = 0.f;
#pragma unroll
    for (int d = 0; d < 16; ++d) {
      sl += f[d] * aw[hh * 32 + d];
      sr += f[d] * aw[hh * 32 + 16 + d];
    }
    s_l[((size_t)r * NN + n) * NH + hh] = sl;
    s_r[((size_t)r * NN + n) * NH + hh] = sr;
  }
}

// ---------- kernel 3: degree histogram ----------
__global__ __launch_bounds__(256) void hist_kernel(const int* __restrict__ dst,
                                                   int* __restrict__ deg) {
  int e = blockIdx.x * blockDim.x + threadIdx.x;
  if (e < NE) atomicAdd(&deg[dst[e]], 1);
}

// ---------- kernel 4: exclusive prefix sum (single block) ----------
__global__ __launch_bounds__(256) void scan_kernel(const int* __restrict__ deg,
                                                   int* __restrict__ row_start) {
  __shared__ int part[256];
  int t = threadIdx.x;
  const int CH = (NN + 255) / 256;  // 196
  int lo = t * CH, hi = min(lo + CH, NN);
  int s = 0;
  for (int i = lo; i < hi; ++i) s += deg[i];
  part[t] = s;
  __syncthreads();
  for (int off = 1; off < 256; off <<= 1) {
    int v = (t >= off) ? part[t - off] : 0;
    __syncthreads();
    part[t] += v;
    __syncthreads();
  }
  int base = (t == 0) ? 0 : part[t - 1];
  for (int i = lo; i < hi; ++i) {
    row_start[i] = base;
    base += deg[i];
  }
  if (t == 255) row_start[NN] = base;
}

// ---------- kernel 5: scatter edges into CSR order, fold scores ----------
__global__ __launch_bounds__(256) void scatter_kernel(
    const int* __restrict__ src, const int* __restrict__ dst,
    const int* __restrict__ et, const float* __restrict__ s_l,
    const float* __restrict__ s_r, const int* __restrict__ row_start,
    int* __restrict__ cursor, unsigned short* __restrict__ es,
    unsigned* __restrict__ sidx) {
  int e = blockIdx.x * blockDim.x + threadIdx.x;
  if (e >= NE) return;
  int s = src[e], d = dst[e], r = et[e];
  int pos = row_start[d] + atomicAdd(&cursor[d], 1);
  const float4* slp = (const float4*)&s_l[((size_t)r * NN + s) * NH];
  const float4* srp = (const float4*)&s_r[((size_t)r * NN + d) * NH];
  float4 a0 = slp[0], a1 = slp[1], b0 = srp[0], b1 = srp[1];
  float ev[8] = {a0.x + b0.x, a0.y + b0.y, a0.z + b0.z, a0.w + b0.w,
                 a1.x + b1.x, a1.y + b1.y, a1.z + b1.z, a1.w + b1.w};
  ushort4 w0, w1;
  unsigned short wv[8];
#pragma unroll
  for (int hh = 0; hh < 8; ++hh) {
    float x = ev[hh];
    x = x > 0.f ? x : 0.01f * x;
    wv[hh] = f2bf(x);
  }
  w0.x = wv[0]; w0.y = wv[1]; w0.z = wv[2]; w0.w = wv[3];
  w1.x = wv[4]; w1.y = wv[5]; w1.z = wv[6]; w1.w = wv[7];
  *(ushort4*)&es[(size_t)pos * 8] = w0;
  *(ushort4*)&es[(size_t)pos * 8 + 4] = w1;
  sidx[pos] = (unsigned)s | ((unsigned)r << 16);
}

// ---------- kernel 6: per-node softmax + weighted gather (1 wave/node) ----------
__global__ __launch_bounds__(256) void node_accum(
    const int* __restrict__ row_start, const unsigned short* __restrict__ es,
    const unsigned* __restrict__ sidx, const unsigned short* __restrict__ z,
    float* __restrict__ out) {
  int wave = threadIdx.x >> 6;
  int lane = threadIdx.x & 63;
  int n = blockIdx.x * 4 + wave;
  if (n >= NN) return;
  int b0 = row_start[n];
  int deg = row_start[n + 1] - b0;

  int hl = lane & 7;   // head this lane scores
  int jg = lane >> 3;  // edge slot within chunk of 8
  int ho = lane >> 3;  // head of this lane's output elements (2*lane, 2*lane+1)

  // pass 1: per-head max
  float maxv = -INFINITY;
  for (int j = jg; j < deg; j += 8)
    maxv = fmaxf(maxv, bf2f(es[(size_t)(b0 + j) * 8 + hl]));
#pragma unroll
  for (int m = 8; m < 64; m <<= 1) maxv = fmaxf(maxv, __shfl_xor(maxv, m));
  // maxv now holds m[hl] in every lane

  float2 acc = make_float2(0.f, 0.f);
  float den = 0.f;

  for (int c = 0; c < deg; c += 8) {
    int j = c + jg;
    float ex = 0.f;
    if (j < deg) ex = __expf(bf2f(es[(size_t)(b0 + j) * 8 + hl]) - maxv);
    den += ex;
    int rem = min(8, deg - c);
    // packed (src|r<<16) for this chunk; clamp so every lane holds a valid row
    unsigned pk = sidx[b0 + c + min(lane & 7, rem - 1)];
#pragma unroll
    for (int jj = 0; jj < 8; ++jj) {
      if (jj >= rem) break;
      float exb = __shfl(ex, (jj << 3) | ho);
      unsigned p = __shfl(pk, jj);
      unsigned sr_ = p & 0xFFFFu;
      unsigned rr = p >> 16;
      unsigned u = *(const unsigned*)&z[(((size_t)rr * NN + sr_) << 7) + 2 * lane];
      acc.x += exb * __uint_as_float((u & 0xFFFFu) << 16);
      acc.y += exb * __uint_as_float(u & 0xFFFF0000u);
    }
  }
#pragma unroll
  for (int m = 8; m < 64; m <<= 1) den += __shfl_xor(den, m);
  float deno = __shfl(den, ho);
  float inv = 1.0f / fmaxf(deno, 1e-9f);
  *(float2*)&out[((size_t)n << 7) + 2 * lane] =
      make_float2(acc.x * inv, acc.y * inv);
}

extern "C" void kernel_launch(void* const* d_in, const int* in_sizes, int n_in,
                              void* d_out, int out_size, void* d_ws, size_t ws_size,
                              hipStream_t stream) {
  const float* h = (const float*)d_in[0];
  const float* fc = (const float*)d_in[1];
  const float* attn = (const float*)d_in[2];
  const int* src = (const int*)d_in[3];
  const int* dst = (const int*)d_in[4];
  const int* et = (const int*)d_in[5];
  float* out = (float*)d_out;

  // workspace layout
  char* wsb = (char*)d_ws;
  unsigned short* z = (unsigned short*)wsb;  // 102.4 MB
  size_t off = (size_t)NR * NN * DOUT * sizeof(unsigned short);
  float* s_l = (float*)(wsb + off); off += (size_t)NR * NN * NH * sizeof(float);  // 12.8 MB
  float* s_r = (float*)(wsb + off); off += (size_t)NR * NN * NH * sizeof(float);  // 12.8 MB
  int* deg = (int*)(wsb + off); off += (size_t)NN * sizeof(int);
  int* row_start = (int*)(wsb + off); off += (size_t)(NN + 1) * sizeof(int);
  int* cursor = (int*)(wsb + off); off += (size_t)NN * sizeof(int);
  unsigned short* es = (unsigned short*)(wsb + off); off += (size_t)NE * NH * sizeof(unsigned short);  // 12.8 MB
  unsigned* sidx = (unsigned*)(wsb + off); off += (size_t)NE * sizeof(unsigned);  // 3.2 MB

  hipMemsetAsync(deg, 0, (size_t)NN * sizeof(int), stream);
  hipMemsetAsync(cursor, 0, (size_t)NN * sizeof(int), stream);

  dim3 ggrid((NN + 63) / 64, 2, NR);
  gemm_z<<<ggrid, 256, 0, stream>>>(h, fc, z);

  scores_kernel<<<(NR * NN + 255) / 256, 256, 0, stream>>>(z, attn, s_l, s_r);

  hist_kernel<<<(NE + 255) / 256, 256, 0, stream>>>(dst, deg);
  scan_kernel<<<1, 256, 0, stream>>>(deg, row_start);
  scatter_kernel<<<(NE + 255) / 256, 256, 0, stream>>>(src, dst, et, s_l, s_r,
                                                       row_start, cursor, es, sidx);

  node_accum<<<(NN + 3) / 4, 256, 0, stream>>>(row_start, es, sidx, z, out);
}

// Round 3
// 405.804 us; speedup vs baseline: 15.6207x; 1.3920x over previous
//
#include <hip/hip_runtime.h>

#define NN 50000
#define NE 800000
#define NR 8
#define DIN 128
#define DOUT 128
#define NH 8

typedef __attribute__((ext_vector_type(8))) short bf16x8;
typedef __attribute__((ext_vector_type(4))) float f32x4;

// ---------- helpers ----------
__device__ __forceinline__ unsigned short f2bf(float f) {
  unsigned u = __float_as_uint(f);
  unsigned r = (u + 0x7FFFu + ((u >> 16) & 1u)) >> 16;
  return (unsigned short)r;
}
__device__ __forceinline__ float bf2f(unsigned short b) {
  return __uint_as_float(((unsigned)b) << 16);
}

// ---------- prep: h -> bf16 ----------
__global__ __launch_bounds__(256) void prep_hb(const float* __restrict__ h,
                                               unsigned short* __restrict__ hb) {
  int i = blockIdx.x * 256 + threadIdx.x;
  if (i >= NN * DIN / 8) return;
  const float4* p = (const float4*)(h + (size_t)i * 8);
  float4 v0 = p[0], v1 = p[1];
  ushort4 w0, w1;
  w0.x = f2bf(v0.x); w0.y = f2bf(v0.y); w0.z = f2bf(v0.z); w0.w = f2bf(v0.w);
  w1.x = f2bf(v1.x); w1.y = f2bf(v1.y); w1.z = f2bf(v1.z); w1.w = f2bf(v1.w);
  ushort4* o = (ushort4*)(hb + (size_t)i * 8);
  o[0] = w0; o[1] = w1;
}

// ---------- prep: B-ext = [fc[r] | fc[r]@W2] in MFMA fragment order ----------
// fcf[r][t][ks][g][c][i] = B[k = ks*32+g*8+i][o = t*16+c], bf16
// t=8 cols: j = p*8+h: sum_d fc[r][k][16h+d]*aw[r][h][16p+d]
__global__ __launch_bounds__(256) void prep_fcf(
    const float* __restrict__ fc, const float* __restrict__ attn,
    unsigned short* __restrict__ fcf) {
  int idx = blockIdx.x * 256 + threadIdx.x;
  if (idx >= NR * DIN * 144) return;
  int r = idx / (DIN * 144);
  int rem = idx - r * (DIN * 144);
  int k = rem / 144;
  int j = rem - k * 144;
  float v;
  if (j < DOUT) {
    v = fc[((size_t)r * DIN + k) * DOUT + j];
  } else {
    int cc = j - DOUT;  // 0..15
    int hh = cc & 7, p = cc >> 3;
    const float* fr = fc + ((size_t)r * DIN + k) * DOUT + hh * 16;
    const float* ar = attn + ((size_t)r * NH + hh) * 32 + p * 16;
    v = 0.f;
#pragma unroll
    for (int d = 0; d < 16; ++d) v += fr[d] * ar[d];
  }
  int t = j >> 4, c = j & 15, ks = k >> 5, gg = (k >> 3) & 3, i = k & 7;
  fcf[((((size_t)r * 9 + t) * 4 + ks) * 4 + gg) * 128 + c * 8 + i] = f2bf(v);
}

// ---------- kernel 1: MFMA GEMM, z + fused scores ----------
// block: 4 waves x 16 rows; wave computes 16 rows x 144 cols (9 tiles), K=128
__global__ __launch_bounds__(256) void gemm_mfma(
    const unsigned short* __restrict__ hb, const unsigned short* __restrict__ fcf,
    unsigned short* __restrict__ z, float* __restrict__ s_buf) {
  const int r = blockIdx.y;
  const int n0 = blockIdx.x * 64;
  const int w = threadIdx.x >> 6;
  const int lane = threadIdx.x & 63;
  const int g = lane >> 4, c = lane & 15;
  const int nbase = n0 + w * 16;

  // B fragments: 36 coalesced 16B loads (L2-resident)
  bf16x8 bf[9][4];
  const unsigned short* fb = fcf + ((size_t)r * 36 * 64 + lane) * 8;
#pragma unroll
  for (int t = 0; t < 9; ++t)
#pragma unroll
    for (int ks = 0; ks < 4; ++ks)
      bf[t][ks] = *(const bf16x8*)(fb + (size_t)(t * 4 + ks) * 512);

  // A fragments: row = nbase + c, k = ks*32 + g*8 + i  (matches B k-indexing)
  int arow = nbase + c;
  if (arow > NN - 1) arow = NN - 1;
  const unsigned short* ha = hb + (size_t)arow * DIN + g * 8;
  bf16x8 af[4];
#pragma unroll
  for (int ks = 0; ks < 4; ++ks) af[ks] = *(const bf16x8*)(ha + ks * 32);

  f32x4 acc[9];
#pragma unroll
  for (int t = 0; t < 9; ++t) acc[t] = (f32x4){0.f, 0.f, 0.f, 0.f};

#pragma unroll
  for (int ks = 0; ks < 4; ++ks)
#pragma unroll
    for (int t = 0; t < 9; ++t)
      acc[t] = __builtin_amdgcn_mfma_f32_16x16x32_bf16(af[ks], bf[t][ks], acc[t], 0, 0, 0);

  // epilogue: C/D layout col=lane&15, row=(lane>>4)*4+q  [m89-verified]
#pragma unroll
  for (int q = 0; q < 4; ++q) {
    int node = nbase + g * 4 + q;
    if (node < NN) {
      unsigned short* zr = z + ((size_t)r * NN + node) * DOUT + c;
#pragma unroll
      for (int t = 0; t < 8; ++t) zr[t * 16] = f2bf(acc[t][q]);
      s_buf[((size_t)r * NN + node) * 16 + c] = acc[8][q];
    }
  }
}

// ---------- kernel 2: degree histogram ----------
__global__ __launch_bounds__(256) void hist_kernel(const int* __restrict__ dst,
                                                   int* __restrict__ deg) {
  int e = blockIdx.x * blockDim.x + threadIdx.x;
  if (e < NE) atomicAdd(&deg[dst[e]], 1);
}

// ---------- kernel 3: exclusive prefix sum (single block) ----------
__global__ __launch_bounds__(256) void scan_kernel(const int* __restrict__ deg,
                                                   int* __restrict__ row_start) {
  __shared__ int part[256];
  int t = threadIdx.x;
  const int CH = (NN + 255) / 256;
  int lo = t * CH, hi = min(lo + CH, NN);
  int s = 0;
  for (int i = lo; i < hi; ++i) s += deg[i];
  part[t] = s;
  __syncthreads();
  for (int off = 1; off < 256; off <<= 1) {
    int v = (t >= off) ? part[t - off] : 0;
    __syncthreads();
    part[t] += v;
    __syncthreads();
  }
  int base = (t == 0) ? 0 : part[t - 1];
  for (int i = lo; i < hi; ++i) {
    row_start[i] = base;
    base += deg[i];
  }
  if (t == 255) row_start[NN] = base;
}

// ---------- kernel 4: scatter edges into CSR order, fold leaky-relu ----------
__global__ __launch_bounds__(256) void scatter_kernel(
    const int* __restrict__ src, const int* __restrict__ dst,
    const int* __restrict__ et, const float* __restrict__ s_buf,
    const int* __restrict__ row_start, int* __restrict__ cursor,
    unsigned short* __restrict__ es, unsigned* __restrict__ sidx) {
  int e = blockIdx.x * blockDim.x + threadIdx.x;
  if (e >= NE) return;
  int s = src[e], d = dst[e], r = et[e];
  int pos = row_start[d] + atomicAdd(&cursor[d], 1);
  const float4* sp = (const float4*)&s_buf[((size_t)r * NN + s) * 16];
  const float4* dp = (const float4*)&s_buf[((size_t)r * NN + d) * 16 + 8];
  float4 a0 = sp[0], a1 = sp[1], b0 = dp[0], b1 = dp[1];
  float ev[8] = {a0.x + b0.x, a0.y + b0.y, a0.z + b0.z, a0.w + b0.w,
                 a1.x + b1.x, a1.y + b1.y, a1.z + b1.z, a1.w + b1.w};
  ushort4 w0, w1;
  unsigned short wv[8];
#pragma unroll
  for (int hh = 0; hh < 8; ++hh) {
    float x = ev[hh];
    x = x > 0.f ? x : 0.01f * x;
    wv[hh] = f2bf(x);
  }
  w0.x = wv[0]; w0.y = wv[1]; w0.z = wv[2]; w0.w = wv[3];
  w1.x = wv[4]; w1.y = wv[5]; w1.z = wv[6]; w1.w = wv[7];
  *(ushort4*)&es[(size_t)pos * 8] = w0;
  *(ushort4*)&es[(size_t)pos * 8 + 4] = w1;
  sidx[pos] = (unsigned)s | ((unsigned)r << 16);
}

// ---------- kernel 5: per-node softmax + weighted gather (1 wave/node) ----------
__global__ __launch_bounds__(256) void node_accum(
    const int* __restrict__ row_start, const unsigned short* __restrict__ es,
    const unsigned* __restrict__ sidx, const unsigned short* __restrict__ z,
    float* __restrict__ out) {
  int wave = threadIdx.x >> 6;
  int lane = threadIdx.x & 63;
  int n = blockIdx.x * 4 + wave;
  if (n >= NN) return;
  int b0 = row_start[n];
  int deg = row_start[n + 1] - b0;

  int hl = lane & 7;
  int jg = lane >> 3;
  int ho = lane >> 3;

  float maxv = -INFINITY;
  for (int j = jg; j < deg; j += 8)
    maxv = fmaxf(maxv, bf2f(es[(size_t)(b0 + j) * 8 + hl]));
#pragma unroll
  for (int m = 8; m < 64; m <<= 1) maxv = fmaxf(maxv, __shfl_xor(maxv, m));

  float2 acc = make_float2(0.f, 0.f);
  float den = 0.f;

  for (int cch = 0; cch < deg; cch += 8) {
    int j = cch + jg;
    float ex = 0.f;
    if (j < deg) ex = __expf(bf2f(es[(size_t)(b0 + j) * 8 + hl]) - maxv);
    den += ex;
    int rem = min(8, deg - cch);
    unsigned pk = sidx[b0 + cch + min(lane & 7, rem - 1)];
#pragma unroll
    for (int jj = 0; jj < 8; ++jj) {
      if (jj >= rem) break;
      float exb = __shfl(ex, (jj << 3) | ho);
      unsigned p = __shfl(pk, jj);
      unsigned sr_ = p & 0xFFFFu;
      unsigned rr = p >> 16;
      unsigned u = *(const unsigned*)&z[(((size_t)rr * NN + sr_) << 7) + 2 * lane];
      acc.x += exb * __uint_as_float((u & 0xFFFFu) << 16);
      acc.y += exb * __uint_as_float(u & 0xFFFF0000u);
    }
  }
#pragma unroll
  for (int m = 8; m < 64; m <<= 1) den += __shfl_xor(den, m);
  float deno = __shfl(den, ho);
  float inv = 1.0f / fmaxf(deno, 1e-9f);
  *(float2*)&out[((size_t)n << 7) + 2 * lane] =
      make_float2(acc.x * inv, acc.y * inv);
}

extern "C" void kernel_launch(void* const* d_in, const int* in_sizes, int n_in,
                              void* d_out, int out_size, void* d_ws, size_t ws_size,
                              hipStream_t stream) {
  const float* h = (const float*)d_in[0];
  const float* fc = (const float*)d_in[1];
  const float* attn = (const float*)d_in[2];
  const int* src = (const int*)d_in[3];
  const int* dst = (const int*)d_in[4];
  const int* et = (const int*)d_in[5];
  float* out = (float*)d_out;

  // workspace layout (16B-aligned chunks first)
  char* wsb = (char*)d_ws;
  size_t off = 0;
  unsigned short* z = (unsigned short*)(wsb + off);  off += (size_t)NR * NN * DOUT * 2;      // 102.4 MB
  unsigned short* hb = (unsigned short*)(wsb + off); off += (size_t)NN * DIN * 2;            // 12.8 MB
  float* s_buf = (float*)(wsb + off);                off += (size_t)NR * NN * 16 * 4;        // 25.6 MB
  unsigned short* es = (unsigned short*)(wsb + off); off += (size_t)NE * NH * 2;             // 12.8 MB
  unsigned* sidx = (unsigned*)(wsb + off);           off += (size_t)NE * 4;                  // 3.2 MB
  unsigned short* fcf = (unsigned short*)(wsb + off);off += (size_t)NR * 9 * 4 * 4 * 128 * 2;// 0.3 MB
  int* deg = (int*)(wsb + off);                      off += (size_t)NN * 4;
  int* row_start = (int*)(wsb + off);                off += (size_t)(NN + 1) * 4;
  int* cursor = (int*)(wsb + off);                   off += (size_t)NN * 4;

  hipMemsetAsync(deg, 0, (size_t)NN * sizeof(int), stream);
  hipMemsetAsync(cursor, 0, (size_t)NN * sizeof(int), stream);

  prep_hb<<<(NN * DIN / 8 + 255) / 256, 256, 0, stream>>>(h, hb);
  prep_fcf<<<(NR * DIN * 144 + 255) / 256, 256, 0, stream>>>(fc, attn, fcf);

  dim3 ggrid((NN + 63) / 64, NR);
  gemm_mfma<<<ggrid, 256, 0, stream>>>(hb, fcf, z, s_buf);

  hist_kernel<<<(NE + 255) / 256, 256, 0, stream>>>(dst, deg);
  scan_kernel<<<1, 256, 0, stream>>>(deg, row_start);
  scatter_kernel<<<(NE + 255) / 256, 256, 0, stream>>>(src, dst, et, s_buf,
                                                       row_start, cursor, es, sidx);

  node_accum<<<(NN + 3) / 4, 256, 0, stream>>>(row_start, es, sidx, z, out);
}

// Round 4
// 327.278 us; speedup vs baseline: 19.3688x; 1.2399x over previous
//
#include <hip/hip_runtime.h>

#define NN 50000
#define NE 800000
#define NR 8
#define DIN 128
#define DOUT 128
#define NH 8

#define NB_SCAN ((NN + 255) / 256)  // 196

typedef __attribute__((ext_vector_type(8))) short bf16x8;
typedef __attribute__((ext_vector_type(4))) float f32x4;

// ---------- helpers ----------
__device__ __forceinline__ unsigned short f2bf(float f) {
  unsigned u = __float_as_uint(f);
  unsigned r = (u + 0x7FFFu + ((u >> 16) & 1u)) >> 16;
  return (unsigned short)r;
}
__device__ __forceinline__ float bf2f(unsigned short b) {
  return __uint_as_float(((unsigned)b) << 16);
}

// ---------- prep: h -> bf16 ----------
__global__ __launch_bounds__(256) void prep_hb(const float* __restrict__ h,
                                               unsigned short* __restrict__ hb) {
  int i = blockIdx.x * 256 + threadIdx.x;
  if (i >= NN * DIN / 8) return;
  const float4* p = (const float4*)(h + (size_t)i * 8);
  float4 v0 = p[0], v1 = p[1];
  ushort4 w0, w1;
  w0.x = f2bf(v0.x); w0.y = f2bf(v0.y); w0.z = f2bf(v0.z); w0.w = f2bf(v0.w);
  w1.x = f2bf(v1.x); w1.y = f2bf(v1.y); w1.z = f2bf(v1.z); w1.w = f2bf(v1.w);
  ushort4* o = (ushort4*)(hb + (size_t)i * 8);
  o[0] = w0; o[1] = w1;
}

// ---------- prep: B-ext = [fc[r] | fc[r]@W2] in MFMA fragment order ----------
__global__ __launch_bounds__(256) void prep_fcf(
    const float* __restrict__ fc, const float* __restrict__ attn,
    unsigned short* __restrict__ fcf) {
  int idx = blockIdx.x * 256 + threadIdx.x;
  if (idx >= NR * DIN * 144) return;
  int r = idx / (DIN * 144);
  int rem = idx - r * (DIN * 144);
  int k = rem / 144;
  int j = rem - k * 144;
  float v;
  if (j < DOUT) {
    v = fc[((size_t)r * DIN + k) * DOUT + j];
  } else {
    int cc = j - DOUT;  // 0..15
    int hh = cc & 7, p = cc >> 3;
    const float* fr = fc + ((size_t)r * DIN + k) * DOUT + hh * 16;
    const float* ar = attn + ((size_t)r * NH + hh) * 32 + p * 16;
    v = 0.f;
#pragma unroll
    for (int d = 0; d < 16; ++d) v += fr[d] * ar[d];
  }
  int t = j >> 4, c = j & 15, ks = k >> 5, gg = (k >> 3) & 3, i = k & 7;
  fcf[((((size_t)r * 9 + t) * 4 + ks) * 4 + gg) * 128 + c * 8 + i] = f2bf(v);
}

// ---------- kernel 1: MFMA GEMM, z + fused scores ----------
__global__ __launch_bounds__(256) void gemm_mfma(
    const unsigned short* __restrict__ hb, const unsigned short* __restrict__ fcf,
    unsigned short* __restrict__ z, float* __restrict__ s_buf) {
  const int r = blockIdx.y;
  const int n0 = blockIdx.x * 64;
  const int w = threadIdx.x >> 6;
  const int lane = threadIdx.x & 63;
  const int g = lane >> 4, c = lane & 15;
  const int nbase = n0 + w * 16;

  bf16x8 bf[9][4];
  const unsigned short* fb = fcf + ((size_t)r * 36 * 64 + lane) * 8;
#pragma unroll
  for (int t = 0; t < 9; ++t)
#pragma unroll
    for (int ks = 0; ks < 4; ++ks)
      bf[t][ks] = *(const bf16x8*)(fb + (size_t)(t * 4 + ks) * 512);

  int arow = nbase + c;
  if (arow > NN - 1) arow = NN - 1;
  const unsigned short* ha = hb + (size_t)arow * DIN + g * 8;
  bf16x8 af[4];
#pragma unroll
  for (int ks = 0; ks < 4; ++ks) af[ks] = *(const bf16x8*)(ha + ks * 32);

  f32x4 acc[9];
#pragma unroll
  for (int t = 0; t < 9; ++t) acc[t] = (f32x4){0.f, 0.f, 0.f, 0.f};

#pragma unroll
  for (int ks = 0; ks < 4; ++ks)
#pragma unroll
    for (int t = 0; t < 9; ++t)
      acc[t] = __builtin_amdgcn_mfma_f32_16x16x32_bf16(af[ks], bf[t][ks], acc[t], 0, 0, 0);

#pragma unroll
  for (int q = 0; q < 4; ++q) {
    int node = nbase + g * 4 + q;
    if (node < NN) {
      unsigned short* zr = z + ((size_t)r * NN + node) * DOUT + c;
#pragma unroll
      for (int t = 0; t < 8; ++t) zr[t * 16] = f2bf(acc[t][q]);
      s_buf[((size_t)r * NN + node) * 16 + c] = acc[8][q];
    }
  }
}

// ---------- kernel 2: degree histogram ----------
__global__ __launch_bounds__(256) void hist_kernel(const int* __restrict__ dst,
                                                   int* __restrict__ deg) {
  int e = blockIdx.x * blockDim.x + threadIdx.x;
  if (e < NE) atomicAdd(&deg[dst[e]], 1);
}

// ---------- kernel 3a: per-block sums of deg ----------
__global__ __launch_bounds__(256) void scan1(const int* __restrict__ deg,
                                             int* __restrict__ bsum) {
  __shared__ int ws_[4];
  int gi = blockIdx.x * 256 + threadIdx.x;
  int v = (gi < NN) ? deg[gi] : 0;
#pragma unroll
  for (int m = 1; m < 64; m <<= 1) v += __shfl_xor(v, m);
  if ((threadIdx.x & 63) == 0) ws_[threadIdx.x >> 6] = v;
  __syncthreads();
  if (threadIdx.x == 0) bsum[blockIdx.x] = ws_[0] + ws_[1] + ws_[2] + ws_[3];
}

// ---------- kernel 3b: scan the 196 block sums (1 block) ----------
__global__ __launch_bounds__(256) void scan2(const int* __restrict__ bsum,
                                             int* __restrict__ bbase,
                                             int* __restrict__ row_start) {
  __shared__ int part[256];
  int t = threadIdx.x;
  part[t] = (t < NB_SCAN) ? bsum[t] : 0;
  __syncthreads();
  for (int off = 1; off < 256; off <<= 1) {
    int v = (t >= off) ? part[t - off] : 0;
    __syncthreads();
    part[t] += v;
    __syncthreads();
  }
  if (t < NB_SCAN) bbase[t] = (t == 0) ? 0 : part[t - 1];
  if (t == 0) row_start[NN] = NE;
}

// ---------- kernel 3c: block-local scan + base -> row_start ----------
__global__ __launch_bounds__(256) void scan3(const int* __restrict__ deg,
                                             const int* __restrict__ bbase,
                                             int* __restrict__ row_start) {
  __shared__ int part[256];
  int t = threadIdx.x;
  int gi = blockIdx.x * 256 + t;
  int v = (gi < NN) ? deg[gi] : 0;
  part[t] = v;
  __syncthreads();
  for (int off = 1; off < 256; off <<= 1) {
    int x = (t >= off) ? part[t - off] : 0;
    __syncthreads();
    part[t] += x;
    __syncthreads();
  }
  if (gi < NN) row_start[gi] = bbase[blockIdx.x] + part[t] - v;
}

// ---------- kernel 4: scatter edges into CSR order, fold leaky-relu ----------
__global__ __launch_bounds__(256) void scatter_kernel(
    const int* __restrict__ src, const int* __restrict__ dst,
    const int* __restrict__ et, const float* __restrict__ s_buf,
    const int* __restrict__ row_start, int* __restrict__ cursor,
    unsigned short* __restrict__ es, unsigned* __restrict__ sidx) {
  int e = blockIdx.x * blockDim.x + threadIdx.x;
  if (e >= NE) return;
  int s = src[e], d = dst[e], r = et[e];
  int pos = row_start[d] + atomicAdd(&cursor[d], 1);
  const float4* sp = (const float4*)&s_buf[((size_t)r * NN + s) * 16];
  const float4* dp = (const float4*)&s_buf[((size_t)r * NN + d) * 16 + 8];
  float4 a0 = sp[0], a1 = sp[1], b0 = dp[0], b1 = dp[1];
  float ev[8] = {a0.x + b0.x, a0.y + b0.y, a0.z + b0.z, a0.w + b0.w,
                 a1.x + b1.x, a1.y + b1.y, a1.z + b1.z, a1.w + b1.w};
  ushort4 w0, w1;
  unsigned short wv[8];
#pragma unroll
  for (int hh = 0; hh < 8; ++hh) {
    float x = ev[hh];
    x = x > 0.f ? x : 0.01f * x;
    wv[hh] = f2bf(x);
  }
  w0.x = wv[0]; w0.y = wv[1]; w0.z = wv[2]; w0.w = wv[3];
  w1.x = wv[4]; w1.y = wv[5]; w1.z = wv[6]; w1.w = wv[7];
  *(ushort4*)&es[(size_t)pos * 8] = w0;
  *(ushort4*)&es[(size_t)pos * 8 + 4] = w1;
  sidx[pos] = (unsigned)s | ((unsigned)r << 16);
}

// ---------- kernel 5: per-node softmax + weighted gather (1 wave/node) ----------
__global__ __launch_bounds__(256) void node_accum(
    const int* __restrict__ row_start, const unsigned short* __restrict__ es,
    const unsigned* __restrict__ sidx, const unsigned short* __restrict__ z,
    float* __restrict__ out) {
  int wave = threadIdx.x >> 6;
  int lane = threadIdx.x & 63;
  int n = blockIdx.x * 4 + wave;
  if (n >= NN) return;
  int b0 = row_start[n];
  int deg = row_start[n + 1] - b0;

  int hl = lane & 7;
  int jg = lane >> 3;
  int ho = lane >> 3;

  float maxv = -INFINITY;
  for (int j = jg; j < deg; j += 8)
    maxv = fmaxf(maxv, bf2f(es[(size_t)(b0 + j) * 8 + hl]));
#pragma unroll
  for (int m = 8; m < 64; m <<= 1) maxv = fmaxf(maxv, __shfl_xor(maxv, m));

  float2 acc = make_float2(0.f, 0.f);
  float den = 0.f;

  for (int cch = 0; cch < deg; cch += 8) {
    int j = cch + jg;
    float ex = 0.f;
    if (j < deg) ex = __expf(bf2f(es[(size_t)(b0 + j) * 8 + hl]) - maxv);
    den += ex;
    int rem = min(8, deg - cch);
    unsigned pk = sidx[b0 + cch + min(lane & 7, rem - 1)];
#pragma unroll
    for (int jj = 0; jj < 8; ++jj) {
      if (jj >= rem) break;
      float exb = __shfl(ex, (jj << 3) | ho);
      unsigned p = __shfl(pk, jj);
      unsigned sr_ = p & 0xFFFFu;
      unsigned rr = p >> 16;
      unsigned u = *(const unsigned*)&z[(((size_t)rr * NN + sr_) << 7) + 2 * lane];
      acc.x += exb * __uint_as_float((u & 0xFFFFu) << 16);
      acc.y += exb * __uint_as_float(u & 0xFFFF0000u);
    }
  }
#pragma unroll
  for (int m = 8; m < 64; m <<= 1) den += __shfl_xor(den, m);
  float deno = __shfl(den, ho);
  float inv = 1.0f / fmaxf(deno, 1e-9f);
  *(float2*)&out[((size_t)n << 7) + 2 * lane] =
      make_float2(acc.x * inv, acc.y * inv);
}

extern "C" void kernel_launch(void* const* d_in, const int* in_sizes, int n_in,
                              void* d_out, int out_size, void* d_ws, size_t ws_size,
                              hipStream_t stream) {
  const float* h = (const float*)d_in[0];
  const float* fc = (const float*)d_in[1];
  const float* attn = (const float*)d_in[2];
  const int* src = (const int*)d_in[3];
  const int* dst = (const int*)d_in[4];
  const int* et = (const int*)d_in[5];
  float* out = (float*)d_out;

  // workspace layout (16B-aligned chunks first)
  char* wsb = (char*)d_ws;
  size_t off = 0;
  unsigned short* z = (unsigned short*)(wsb + off);  off += (size_t)NR * NN * DOUT * 2;      // 102.4 MB
  unsigned short* hb = (unsigned short*)(wsb + off); off += (size_t)NN * DIN * 2;            // 12.8 MB
  float* s_buf = (float*)(wsb + off);                off += (size_t)NR * NN * 16 * 4;        // 25.6 MB
  unsigned short* es = (unsigned short*)(wsb + off); off += (size_t)NE * NH * 2;             // 12.8 MB
  unsigned* sidx = (unsigned*)(wsb + off);           off += (size_t)NE * 4;                  // 3.2 MB
  unsigned short* fcf = (unsigned short*)(wsb + off);off += (size_t)NR * 9 * 4 * 4 * 128 * 2;// 0.3 MB
  int* deg = (int*)(wsb + off);                      off += (size_t)NN * 4;
  int* row_start = (int*)(wsb + off);                off += (size_t)(NN + 1) * 4;
  int* cursor = (int*)(wsb + off);                   off += (size_t)NN * 4;
  int* bsum = (int*)(wsb + off);                     off += (size_t)NB_SCAN * 4;
  int* bbase = (int*)(wsb + off);                    off += (size_t)NB_SCAN * 4;

  hipMemsetAsync(deg, 0, (size_t)NN * sizeof(int), stream);
  hipMemsetAsync(cursor, 0, (size_t)NN * sizeof(int), stream);

  prep_hb<<<(NN * DIN / 8 + 255) / 256, 256, 0, stream>>>(h, hb);
  prep_fcf<<<(NR * DIN * 144 + 255) / 256, 256, 0, stream>>>(fc, attn, fcf);

  dim3 ggrid((NN + 63) / 64, NR);
  gemm_mfma<<<ggrid, 256, 0, stream>>>(hb, fcf, z, s_buf);

  hist_kernel<<<(NE + 255) / 256, 256, 0, stream>>>(dst, deg);
  scan1<<<NB_SCAN, 256, 0, stream>>>(deg, bsum);
  scan2<<<1, 256, 0, stream>>>(bsum, bbase, row_start);
  scan3<<<NB_SCAN, 256, 0, stream>>>(deg, bbase, row_start);

  scatter_kernel<<<(NE + 255) / 256, 256, 0, stream>>>(src, dst, et, s_buf,
                                                       row_start, cursor, es, sidx);

  node_accum<<<(NN + 3) / 4, 256, 0, stream>>>(row_start, es, sidx, z, out);
}

// Round 5
// 311.831 us; speedup vs baseline: 20.3282x; 1.0495x over previous
//
#include <hip/hip_runtime.h>

#define NN 50000
#define NE 800000
#define NR 8
#define DIN 128
#define DOUT 128
#define NH 8

#define NB_SCAN ((NN + 255) / 256)  // 196

typedef __attribute__((ext_vector_type(8))) short bf16x8;
typedef __attribute__((ext_vector_type(4))) float f32x4;

// ---------- helpers ----------
__device__ __forceinline__ unsigned short f2bf(float f) {
  unsigned u = __float_as_uint(f);
  unsigned r = (u + 0x7FFFu + ((u >> 16) & 1u)) >> 16;
  return (unsigned short)r;
}
__device__ __forceinline__ float bf2f(unsigned short b) {
  return __uint_as_float(((unsigned)b) << 16);
}

// ---------- prep: h -> bf16 ----------
__global__ __launch_bounds__(256) void prep_hb(const float* __restrict__ h,
                                               unsigned short* __restrict__ hb) {
  int i = blockIdx.x * 256 + threadIdx.x;
  if (i >= NN * DIN / 8) return;
  const float4* p = (const float4*)(h + (size_t)i * 8);
  float4 v0 = p[0], v1 = p[1];
  ushort4 w0, w1;
  w0.x = f2bf(v0.x); w0.y = f2bf(v0.y); w0.z = f2bf(v0.z); w0.w = f2bf(v0.w);
  w1.x = f2bf(v1.x); w1.y = f2bf(v1.y); w1.z = f2bf(v1.z); w1.w = f2bf(v1.w);
  ushort4* o = (ushort4*)(hb + (size_t)i * 8);
  o[0] = w0; o[1] = w1;
}

// ---------- prep: B-ext = [fc[r] | fc[r]@W2] in MFMA fragment order ----------
__global__ __launch_bounds__(256) void prep_fcf(
    const float* __restrict__ fc, const float* __restrict__ attn,
    unsigned short* __restrict__ fcf) {
  int idx = blockIdx.x * 256 + threadIdx.x;
  if (idx >= NR * DIN * 144) return;
  int r = idx / (DIN * 144);
  int rem = idx - r * (DIN * 144);
  int k = rem / 144;
  int j = rem - k * 144;
  float v;
  if (j < DOUT) {
    v = fc[((size_t)r * DIN + k) * DOUT + j];
  } else {
    int cc = j - DOUT;  // 0..15
    int hh = cc & 7, p = cc >> 3;
    const float* fr = fc + ((size_t)r * DIN + k) * DOUT + hh * 16;
    const float* ar = attn + ((size_t)r * NH + hh) * 32 + p * 16;
    v = 0.f;
#pragma unroll
    for (int d = 0; d < 16; ++d) v += fr[d] * ar[d];
  }
  int t = j >> 4, c = j & 15, ks = k >> 5, gg = (k >> 3) & 3, i = k & 7;
  fcf[((((size_t)r * 9 + t) * 4 + ks) * 4 + gg) * 128 + c * 8 + i] = f2bf(v);
}

// ---------- kernel 1: MFMA GEMM (operands swapped -> D[j][node]) ----------
__global__ __launch_bounds__(256) void gemm_mfma(
    const unsigned short* __restrict__ hb, const unsigned short* __restrict__ fcf,
    unsigned short* __restrict__ z, float* __restrict__ s_buf) {
  const int r = blockIdx.y;
  const int n0 = blockIdx.x * 64;
  const int w = threadIdx.x >> 6;
  const int lane = threadIdx.x & 63;
  const int g = lane >> 4, c = lane & 15;
  const int nbase = n0 + w * 16;

  bf16x8 bf[9][4];
  const unsigned short* fb = fcf + ((size_t)r * 36 * 64 + lane) * 8;
#pragma unroll
  for (int t = 0; t < 9; ++t)
#pragma unroll
    for (int ks = 0; ks < 4; ++ks)
      bf[t][ks] = *(const bf16x8*)(fb + (size_t)(t * 4 + ks) * 512);

  int arow = nbase + c;
  if (arow > NN - 1) arow = NN - 1;
  const unsigned short* ha = hb + (size_t)arow * DIN + g * 8;
  bf16x8 af[4];
#pragma unroll
  for (int ks = 0; ks < 4; ++ks) af[ks] = *(const bf16x8*)(ha + ks * 32);

  f32x4 acc[9];
#pragma unroll
  for (int t = 0; t < 9; ++t) acc[t] = (f32x4){0.f, 0.f, 0.f, 0.f};

  // swapped operands: A=bf (j-side), B=af (node-side) -> D row=j_local, col=node
#pragma unroll
  for (int ks = 0; ks < 4; ++ks)
#pragma unroll
    for (int t = 0; t < 9; ++t)
      acc[t] = __builtin_amdgcn_mfma_f32_16x16x32_bf16(bf[t][ks], af[ks], acc[t], 0, 0, 0);

  // lane (g,c) now owns node nbase+c, cols j = t*16 + g*4 + {0..3}
  int node = nbase + c;
  if (node < NN) {
    unsigned short* zr = z + ((size_t)r * NN + node) * DOUT + g * 4;
#pragma unroll
    for (int t = 0; t < 8; ++t) {
      ushort4 wv;
      wv.x = f2bf(acc[t][0]); wv.y = f2bf(acc[t][1]);
      wv.z = f2bf(acc[t][2]); wv.w = f2bf(acc[t][3]);
      *(ushort4*)(zr + t * 16) = wv;
    }
    // score tile t=8: j = 128 + g*4 + q -> s_buf idx g*4+q
    float* sb = s_buf + ((size_t)r * NN + node) * 16 + g * 4;
    *(float4*)sb = make_float4(acc[8][0], acc[8][1], acc[8][2], acc[8][3]);
  }
}

// ---------- kernel 2: degree histogram ----------
__global__ __launch_bounds__(256) void hist_kernel(const int* __restrict__ dst,
                                                   int* __restrict__ deg) {
  int e = blockIdx.x * blockDim.x + threadIdx.x;
  if (e < NE) atomicAdd(&deg[dst[e]], 1);
}

// ---------- kernel 3a: per-block sums of deg ----------
__global__ __launch_bounds__(256) void scan1(const int* __restrict__ deg,
                                             int* __restrict__ bsum) {
  __shared__ int ws_[4];
  int gi = blockIdx.x * 256 + threadIdx.x;
  int v = (gi < NN) ? deg[gi] : 0;
#pragma unroll
  for (int m = 1; m < 64; m <<= 1) v += __shfl_xor(v, m);
  if ((threadIdx.x & 63) == 0) ws_[threadIdx.x >> 6] = v;
  __syncthreads();
  if (threadIdx.x == 0) bsum[blockIdx.x] = ws_[0] + ws_[1] + ws_[2] + ws_[3];
}

// ---------- kernel 3b: scan the 196 block sums (1 block) ----------
__global__ __launch_bounds__(256) void scan2(const int* __restrict__ bsum,
                                             int* __restrict__ bbase,
                                             int* __restrict__ row_start) {
  __shared__ int part[256];
  int t = threadIdx.x;
  part[t] = (t < NB_SCAN) ? bsum[t] : 0;
  __syncthreads();
  for (int off = 1; off < 256; off <<= 1) {
    int v = (t >= off) ? part[t - off] : 0;
    __syncthreads();
    part[t] += v;
    __syncthreads();
  }
  if (t < NB_SCAN) bbase[t] = (t == 0) ? 0 : part[t - 1];
  if (t == 0) row_start[NN] = NE;
}

// ---------- kernel 3c: block-local scan + base -> row_start ----------
__global__ __launch_bounds__(256) void scan3(const int* __restrict__ deg,
                                             const int* __restrict__ bbase,
                                             int* __restrict__ row_start) {
  __shared__ int part[256];
  int t = threadIdx.x;
  int gi = blockIdx.x * 256 + t;
  int v = (gi < NN) ? deg[gi] : 0;
  part[t] = v;
  __syncthreads();
  for (int off = 1; off < 256; off <<= 1) {
    int x = (t >= off) ? part[t - off] : 0;
    __syncthreads();
    part[t] += x;
    __syncthreads();
  }
  if (gi < NN) row_start[gi] = bbase[blockIdx.x] + part[t] - v;
}

// ---------- kernel 4: scatter edges into CSR order, fold leaky-relu ----------
__global__ __launch_bounds__(256) void scatter_kernel(
    const int* __restrict__ src, const int* __restrict__ dst,
    const int* __restrict__ et, const float* __restrict__ s_buf,
    const int* __restrict__ row_start, int* __restrict__ cursor,
    unsigned short* __restrict__ es, unsigned* __restrict__ sidx) {
  int e = blockIdx.x * blockDim.x + threadIdx.x;
  if (e >= NE) return;
  int s = src[e], d = dst[e], r = et[e];
  int pos = row_start[d] + atomicAdd(&cursor[d], 1);
  const float4* sp = (const float4*)&s_buf[((size_t)r * NN + s) * 16];
  const float4* dp = (const float4*)&s_buf[((size_t)r * NN + d) * 16 + 8];
  float4 a0 = sp[0], a1 = sp[1], b0 = dp[0], b1 = dp[1];
  float ev[8] = {a0.x + b0.x, a0.y + b0.y, a0.z + b0.z, a0.w + b0.w,
                 a1.x + b1.x, a1.y + b1.y, a1.z + b1.z, a1.w + b1.w};
  ushort4 w0, w1;
  unsigned short wv[8];
#pragma unroll
  for (int hh = 0; hh < 8; ++hh) {
    float x = ev[hh];
    x = x > 0.f ? x : 0.01f * x;
    wv[hh] = f2bf(x);
  }
  w0.x = wv[0]; w0.y = wv[1]; w0.z = wv[2]; w0.w = wv[3];
  w1.x = wv[4]; w1.y = wv[5]; w1.z = wv[6]; w1.w = wv[7];
  *(ushort4*)&es[(size_t)pos * 8] = w0;
  *(ushort4*)&es[(size_t)pos * 8 + 4] = w1;
  sidx[pos] = (unsigned)s | ((unsigned)r << 16);
}

// ---------- kernel 5: per-node softmax + weighted gather (1 wave/node) ----------
// 4 edges per inner iteration, 16B/lane z-row gathers.
__global__ __launch_bounds__(256) void node_accum(
    const int* __restrict__ row_start, const unsigned short* __restrict__ es,
    const unsigned* __restrict__ sidx, const unsigned short* __restrict__ z,
    float* __restrict__ out) {
  int wave = threadIdx.x >> 6;
  int lane = threadIdx.x & 63;
  int n = blockIdx.x * 4 + wave;
  if (n >= NN) return;
  int b0 = row_start[n];
  int deg = row_start[n + 1] - b0;

  int hl = lane & 7;   // head this lane scores
  int jg = lane >> 3;  // edge slot within chunk of 8 (score pass)
  int c16 = lane & 15; // col-block owner (8 elems at c16*8)
  int e4 = lane >> 4;  // edge-within-4-group this lane gathers

  // pass 1: per-head max
  float maxv = -INFINITY;
  for (int j = jg; j < deg; j += 8)
    maxv = fmaxf(maxv, bf2f(es[(size_t)(b0 + j) * 8 + hl]));
#pragma unroll
  for (int m = 8; m < 64; m <<= 1) maxv = fmaxf(maxv, __shfl_xor(maxv, m));

  float acc[8] = {0.f, 0.f, 0.f, 0.f, 0.f, 0.f, 0.f, 0.f};
  float den = 0.f;
  int hh16 = c16 >> 1;  // head of this lane's 8 output elems

  for (int cch = 0; cch < deg; cch += 8) {
    int j = cch + jg;
    float ex = 0.f;
    if (j < deg) ex = __expf(bf2f(es[(size_t)(b0 + j) * 8 + hl]) - maxv);
    den += ex;
    int rem = min(8, deg - cch);
    unsigned pk = sidx[b0 + cch + min(lane & 7, rem - 1)];
#pragma unroll
    for (int half = 0; half < 2; ++half) {
      if (half * 4 >= rem) break;
      int o = half * 4 + e4;  // edge offset 0..7 handled by this lane
      float exb = __shfl(ex, (o << 3) | hh16);  // 0 for o >= rem
      unsigned p = __shfl(pk, o);               // clamped-valid for o >= rem
      unsigned sr_ = p & 0xFFFFu;
      unsigned rr = p >> 16;
      bf16x8 v = *(const bf16x8*)&z[(((size_t)rr * NN + sr_) << 7) + c16 * 8];
#pragma unroll
      for (int i = 0; i < 8; ++i)
        acc[i] += exb * bf2f((unsigned short)v[i]);
    }
  }
  // den: total per head (lane&7)
#pragma unroll
  for (int m = 8; m < 64; m <<= 1) den += __shfl_xor(den, m);
  // acc: merge the 4 edge-groups (lanes sharing c16)
#pragma unroll
  for (int i = 0; i < 8; ++i) {
    acc[i] += __shfl_xor(acc[i], 16);
    acc[i] += __shfl_xor(acc[i], 32);
  }
  float deno = __shfl(den, hh16);
  float inv = 1.0f / fmaxf(deno, 1e-9f);
  if (lane < 16) {
    float* ob = out + ((size_t)n << 7) + lane * 8;
    *(float4*)ob = make_float4(acc[0] * inv, acc[1] * inv, acc[2] * inv, acc[3] * inv);
    *(float4*)(ob + 4) = make_float4(acc[4] * inv, acc[5] * inv, acc[6] * inv, acc[7] * inv);
  }
}

extern "C" void kernel_launch(void* const* d_in, const int* in_sizes, int n_in,
                              void* d_out, int out_size, void* d_ws, size_t ws_size,
                              hipStream_t stream) {
  const float* h = (const float*)d_in[0];
  const float* fc = (const float*)d_in[1];
  const float* attn = (const float*)d_in[2];
  const int* src = (const int*)d_in[3];
  const int* dst = (const int*)d_in[4];
  const int* et = (const int*)d_in[5];
  float* out = (float*)d_out;

  // workspace layout (16B-aligned chunks first)
  char* wsb = (char*)d_ws;
  size_t off = 0;
  unsigned short* z = (unsigned short*)(wsb + off);  off += (size_t)NR * NN * DOUT * 2;      // 102.4 MB
  unsigned short* hb = (unsigned short*)(wsb + off); off += (size_t)NN * DIN * 2;            // 12.8 MB
  float* s_buf = (float*)(wsb + off);                off += (size_t)NR * NN * 16 * 4;        // 25.6 MB
  unsigned short* es = (unsigned short*)(wsb + off); off += (size_t)NE * NH * 2;             // 12.8 MB
  unsigned* sidx = (unsigned*)(wsb + off);           off += (size_t)NE * 4;                  // 3.2 MB
  unsigned short* fcf = (unsigned short*)(wsb + off);off += (size_t)NR * 9 * 4 * 4 * 128 * 2;// 0.3 MB
  int* deg = (int*)(wsb + off);                      off += (size_t)NN * 4;
  int* row_start = (int*)(wsb + off);                off += (size_t)(NN + 1) * 4;
  int* cursor = (int*)(wsb + off);                   off += (size_t)NN * 4;
  int* bsum = (int*)(wsb + off);                     off += (size_t)NB_SCAN * 4;
  int* bbase = (int*)(wsb + off);                    off += (size_t)NB_SCAN * 4;

  hipMemsetAsync(deg, 0, (size_t)NN * sizeof(int), stream);
  hipMemsetAsync(cursor, 0, (size_t)NN * sizeof(int), stream);

  prep_hb<<<(NN * DIN / 8 + 255) / 256, 256, 0, stream>>>(h, hb);
  prep_fcf<<<(NR * DIN * 144 + 255) / 256, 256, 0, stream>>>(fc, attn, fcf);

  dim3 ggrid((NN + 63) / 64, NR);
  gemm_mfma<<<ggrid, 256, 0, stream>>>(hb, fcf, z, s_buf);

  hist_kernel<<<(NE + 255) / 256, 256, 0, stream>>>(dst, deg);
  scan1<<<NB_SCAN, 256, 0, stream>>>(deg, bsum);
  scan2<<<1, 256, 0, stream>>>(bsum, bbase, row_start);
  scan3<<<NB_SCAN, 256, 0, stream>>>(deg, bbase, row_start);

  scatter_kernel<<<(NE + 255) / 256, 256, 0, stream>>>(src, dst, et, s_buf,
                                                       row_start, cursor, es, sidx);

  node_accum<<<(NN + 3) / 4, 256, 0, stream>>>(row_start, es, sidx, z, out);
}

// Round 6
// 308.108 us; speedup vs baseline: 20.5739x; 1.0121x over previous
//
#include <hip/hip_runtime.h>

#define NN 50000
#define NE 800000
#define NR 8
#define DIN 128
#define DOUT 128
#define NH 8

#define NB_SCAN ((NN + 255) / 256)  // 196

typedef __attribute__((ext_vector_type(8))) short bf16x8;
typedef __attribute__((ext_vector_type(4))) float f32x4;

// ---------- helpers ----------
__device__ __forceinline__ unsigned short f2bf(float f) {
  unsigned u = __float_as_uint(f);
  unsigned r = (u + 0x7FFFu + ((u >> 16) & 1u)) >> 16;
  return (unsigned short)r;
}
__device__ __forceinline__ float bf2f(unsigned short b) {
  return __uint_as_float(((unsigned)b) << 16);
}

// ---------- prep: B-ext = [fc[r] | fc[r]@W2] in MFMA fragment order ----------
__global__ __launch_bounds__(256) void prep_fcf(
    const float* __restrict__ fc, const float* __restrict__ attn,
    unsigned short* __restrict__ fcf) {
  int idx = blockIdx.x * 256 + threadIdx.x;
  if (idx >= NR * DIN * 144) return;
  int r = idx / (DIN * 144);
  int rem = idx - r * (DIN * 144);
  int k = rem / 144;
  int j = rem - k * 144;
  float v;
  if (j < DOUT) {
    v = fc[((size_t)r * DIN + k) * DOUT + j];
  } else {
    int cc = j - DOUT;  // 0..15
    int hh = cc & 7, p = cc >> 3;
    const float* fr = fc + ((size_t)r * DIN + k) * DOUT + hh * 16;
    const float* ar = attn + ((size_t)r * NH + hh) * 32 + p * 16;
    v = 0.f;
#pragma unroll
    for (int d = 0; d < 16; ++d) v += fr[d] * ar[d];
  }
  int t = j >> 4, c = j & 15, ks = k >> 5, gg = (k >> 3) & 3, i = k & 7;
  fcf[((((size_t)r * 9 + t) * 4 + ks) * 4 + gg) * 128 + c * 8 + i] = f2bf(v);
}

// ---------- kernel 1: MFMA GEMM, all relations per block (h read once) ----------
__global__ __launch_bounds__(256) void gemm_mfma(
    const float* __restrict__ h, const unsigned short* __restrict__ fcf,
    unsigned short* __restrict__ z, unsigned short* __restrict__ s_buf) {
  const int n0 = blockIdx.x * 64;
  const int w = threadIdx.x >> 6;
  const int lane = threadIdx.x & 63;
  const int g = lane >> 4, c = lane & 15;
  const int nbase = n0 + w * 16;

  // A fragments: row = nbase + c, k = ks*32 + g*8 + i; convert fp32->bf16 here
  int arow = nbase + c;
  if (arow > NN - 1) arow = NN - 1;
  const float* ha = h + (size_t)arow * DIN + g * 8;
  bf16x8 af[4];
#pragma unroll
  for (int ks = 0; ks < 4; ++ks) {
    float4 v0 = *(const float4*)(ha + ks * 32);
    float4 v1 = *(const float4*)(ha + ks * 32 + 4);
    bf16x8 a;
    a[0] = (short)f2bf(v0.x); a[1] = (short)f2bf(v0.y);
    a[2] = (short)f2bf(v0.z); a[3] = (short)f2bf(v0.w);
    a[4] = (short)f2bf(v1.x); a[5] = (short)f2bf(v1.y);
    a[6] = (short)f2bf(v1.z); a[7] = (short)f2bf(v1.w);
    af[ks] = a;
  }

  const int node = nbase + c;

  for (int r = 0; r < NR; ++r) {
    const unsigned short* fb = fcf + ((size_t)r * 36 * 64 + lane) * 8;
    f32x4 acc[9];
#pragma unroll
    for (int t = 0; t < 9; ++t) acc[t] = (f32x4){0.f, 0.f, 0.f, 0.f};

    // swapped operands: A=bf (j-side), B=af (node-side) -> lane owns node col
#pragma unroll
    for (int ks = 0; ks < 4; ++ks)
#pragma unroll
      for (int t = 0; t < 9; ++t) {
        bf16x8 bf = *(const bf16x8*)(fb + (size_t)(t * 4 + ks) * 512);
        acc[t] = __builtin_amdgcn_mfma_f32_16x16x32_bf16(bf, af[ks], acc[t], 0, 0, 0);
      }

    if (node < NN) {
      unsigned short* zr = z + ((size_t)r * NN + node) * DOUT + g * 4;
#pragma unroll
      for (int t = 0; t < 8; ++t) {
        ushort4 wv;
        wv.x = f2bf(acc[t][0]); wv.y = f2bf(acc[t][1]);
        wv.z = f2bf(acc[t][2]); wv.w = f2bf(acc[t][3]);
        *(ushort4*)(zr + t * 16) = wv;
      }
      ushort4 sv;
      sv.x = f2bf(acc[8][0]); sv.y = f2bf(acc[8][1]);
      sv.z = f2bf(acc[8][2]); sv.w = f2bf(acc[8][3]);
      *(ushort4*)&s_buf[((size_t)r * NN + node) * 16 + g * 4] = sv;
    }
  }
}

// ---------- kernel 2: degree histogram ----------
__global__ __launch_bounds__(256) void hist_kernel(const int* __restrict__ dst,
                                                   int* __restrict__ deg) {
  int e = blockIdx.x * blockDim.x + threadIdx.x;
  if (e < NE) atomicAdd(&deg[dst[e]], 1);
}

// ---------- kernel 3a: per-block sums of deg ----------
__global__ __launch_bounds__(256) void scan1(const int* __restrict__ deg,
                                             int* __restrict__ bsum) {
  __shared__ int ws_[4];
  int gi = blockIdx.x * 256 + threadIdx.x;
  int v = (gi < NN) ? deg[gi] : 0;
#pragma unroll
  for (int m = 1; m < 64; m <<= 1) v += __shfl_xor(v, m);
  if ((threadIdx.x & 63) == 0) ws_[threadIdx.x >> 6] = v;
  __syncthreads();
  if (threadIdx.x == 0) bsum[blockIdx.x] = ws_[0] + ws_[1] + ws_[2] + ws_[3];
}

// ---------- kernel 3b: scan the 196 block sums (1 block) ----------
__global__ __launch_bounds__(256) void scan2(const int* __restrict__ bsum,
                                             int* __restrict__ bbase,
                                             int* __restrict__ row_start) {
  __shared__ int part[256];
  int t = threadIdx.x;
  part[t] = (t < NB_SCAN) ? bsum[t] : 0;
  __syncthreads();
  for (int off = 1; off < 256; off <<= 1) {
    int v = (t >= off) ? part[t - off] : 0;
    __syncthreads();
    part[t] += v;
    __syncthreads();
  }
  if (t < NB_SCAN) bbase[t] = (t == 0) ? 0 : part[t - 1];
  if (t == 0) row_start[NN] = NE;
}

// ---------- kernel 3c: block-local scan + base -> row_start ----------
__global__ __launch_bounds__(256) void scan3(const int* __restrict__ deg,
                                             const int* __restrict__ bbase,
                                             int* __restrict__ row_start) {
  __shared__ int part[256];
  int t = threadIdx.x;
  int gi = blockIdx.x * 256 + t;
  int v = (gi < NN) ? deg[gi] : 0;
  part[t] = v;
  __syncthreads();
  for (int off = 1; off < 256; off <<= 1) {
    int x = (t >= off) ? part[t - off] : 0;
    __syncthreads();
    part[t] += x;
    __syncthreads();
  }
  if (gi < NN) row_start[gi] = bbase[blockIdx.x] + part[t] - v;
}

// ---------- kernel 4: scatter edges into CSR order, fold leaky-relu ----------
__global__ __launch_bounds__(256) void scatter_kernel(
    const int* __restrict__ src, const int* __restrict__ dst,
    const int* __restrict__ et, const unsigned short* __restrict__ s_buf,
    const int* __restrict__ row_start, int* __restrict__ cursor,
    unsigned short* __restrict__ es, unsigned* __restrict__ sidx) {
  int e = blockIdx.x * blockDim.x + threadIdx.x;
  if (e >= NE) return;
  int s = src[e], d = dst[e], r = et[e];
  int pos = row_start[d] + atomicAdd(&cursor[d], 1);
  ushort4 sa0 = *(const ushort4*)&s_buf[((size_t)r * NN + s) * 16];
  ushort4 sa1 = *(const ushort4*)&s_buf[((size_t)r * NN + s) * 16 + 4];
  ushort4 sb0 = *(const ushort4*)&s_buf[((size_t)r * NN + d) * 16 + 8];
  ushort4 sb1 = *(const ushort4*)&s_buf[((size_t)r * NN + d) * 16 + 12];
  float ev[8] = {bf2f(sa0.x) + bf2f(sb0.x), bf2f(sa0.y) + bf2f(sb0.y),
                 bf2f(sa0.z) + bf2f(sb0.z), bf2f(sa0.w) + bf2f(sb0.w),
                 bf2f(sa1.x) + bf2f(sb1.x), bf2f(sa1.y) + bf2f(sb1.y),
                 bf2f(sa1.z) + bf2f(sb1.z), bf2f(sa1.w) + bf2f(sb1.w)};
  ushort4 w0, w1;
  unsigned short wv[8];
#pragma unroll
  for (int hh = 0; hh < 8; ++hh) {
    float x = ev[hh];
    x = x > 0.f ? x : 0.01f * x;
    wv[hh] = f2bf(x);
  }
  w0.x = wv[0]; w0.y = wv[1]; w0.z = wv[2]; w0.w = wv[3];
  w1.x = wv[4]; w1.y = wv[5]; w1.z = wv[6]; w1.w = wv[7];
  *(ushort4*)&es[(size_t)pos * 8] = w0;
  *(ushort4*)&es[(size_t)pos * 8 + 4] = w1;
  sidx[pos] = (unsigned)s | ((unsigned)r << 16);
}

// ---------- kernel 5: per-node softmax + weighted gather (1 wave/node) ----------
// 4 edges per inner iteration, 16B/lane z-row gathers.
__global__ __launch_bounds__(256) void node_accum(
    const int* __restrict__ row_start, const unsigned short* __restrict__ es,
    const unsigned* __restrict__ sidx, const unsigned short* __restrict__ z,
    float* __restrict__ out) {
  int wave = threadIdx.x >> 6;
  int lane = threadIdx.x & 63;
  int n = blockIdx.x * 4 + wave;
  if (n >= NN) return;
  int b0 = row_start[n];
  int deg = row_start[n + 1] - b0;

  int hl = lane & 7;   // head this lane scores
  int jg = lane >> 3;  // edge slot within chunk of 8 (score pass)
  int c16 = lane & 15; // col-block owner (8 elems at c16*8)
  int e4 = lane >> 4;  // edge-within-4-group this lane gathers

  // pass 1: per-head max
  float maxv = -INFINITY;
  for (int j = jg; j < deg; j += 8)
    maxv = fmaxf(maxv, bf2f(es[(size_t)(b0 + j) * 8 + hl]));
#pragma unroll
  for (int m = 8; m < 64; m <<= 1) maxv = fmaxf(maxv, __shfl_xor(maxv, m));

  float acc[8] = {0.f, 0.f, 0.f, 0.f, 0.f, 0.f, 0.f, 0.f};
  float den = 0.f;
  int hh16 = c16 >> 1;  // head of this lane's 8 output elems

  for (int cch = 0; cch < deg; cch += 8) {
    int j = cch + jg;
    float ex = 0.f;
    if (j < deg) ex = __expf(bf2f(es[(size_t)(b0 + j) * 8 + hl]) - maxv);
    den += ex;
    int rem = min(8, deg - cch);
    unsigned pk = sidx[b0 + cch + min(lane & 7, rem - 1)];
#pragma unroll
    for (int half = 0; half < 2; ++half) {
      if (half * 4 >= rem) break;
      int o = half * 4 + e4;  // edge offset 0..7 handled by this lane
      float exb = __shfl(ex, (o << 3) | hh16);  // 0 for o >= rem
      unsigned p = __shfl(pk, o);               // clamped-valid for o >= rem
      unsigned sr_ = p & 0xFFFFu;
      unsigned rr = p >> 16;
      bf16x8 v = *(const bf16x8*)&z[(((size_t)rr * NN + sr_) << 7) + c16 * 8];
#pragma unroll
      for (int i = 0; i < 8; ++i)
        acc[i] += exb * bf2f((unsigned short)v[i]);
    }
  }
  // den: total per head (lane&7)
#pragma unroll
  for (int m = 8; m < 64; m <<= 1) den += __shfl_xor(den, m);
  // acc: merge the 4 edge-groups (lanes sharing c16)
#pragma unroll
  for (int i = 0; i < 8; ++i) {
    acc[i] += __shfl_xor(acc[i], 16);
    acc[i] += __shfl_xor(acc[i], 32);
  }
  float deno = __shfl(den, hh16);
  float inv = 1.0f / fmaxf(deno, 1e-9f);
  if (lane < 16) {
    float* ob = out + ((size_t)n << 7) + lane * 8;
    *(float4*)ob = make_float4(acc[0] * inv, acc[1] * inv, acc[2] * inv, acc[3] * inv);
    *(float4*)(ob + 4) = make_float4(acc[4] * inv, acc[5] * inv, acc[6] * inv, acc[7] * inv);
  }
}

extern "C" void kernel_launch(void* const* d_in, const int* in_sizes, int n_in,
                              void* d_out, int out_size, void* d_ws, size_t ws_size,
                              hipStream_t stream) {
  const float* h = (const float*)d_in[0];
  const float* fc = (const float*)d_in[1];
  const float* attn = (const float*)d_in[2];
  const int* src = (const int*)d_in[3];
  const int* dst = (const int*)d_in[4];
  const int* et = (const int*)d_in[5];
  float* out = (float*)d_out;

  // workspace layout (16B-aligned chunks first)
  char* wsb = (char*)d_ws;
  size_t off = 0;
  unsigned short* z = (unsigned short*)(wsb + off);    off += (size_t)NR * NN * DOUT * 2;      // 102.4 MB
  unsigned short* s_buf = (unsigned short*)(wsb + off);off += (size_t)NR * NN * 16 * 2;        // 12.8 MB
  unsigned short* es = (unsigned short*)(wsb + off);   off += (size_t)NE * NH * 2;             // 12.8 MB
  unsigned* sidx = (unsigned*)(wsb + off);             off += (size_t)NE * 4;                  // 3.2 MB
  unsigned short* fcf = (unsigned short*)(wsb + off);  off += (size_t)NR * 9 * 4 * 4 * 128 * 2;// 0.3 MB
  int* deg = (int*)(wsb + off);                        off += (size_t)NN * 4;
  int* row_start = (int*)(wsb + off);                  off += (size_t)(NN + 1) * 4;
  int* cursor = (int*)(wsb + off);                     off += (size_t)NN * 4;
  int* bsum = (int*)(wsb + off);                       off += (size_t)NB_SCAN * 4;
  int* bbase = (int*)(wsb + off);                      off += (size_t)NB_SCAN * 4;

  hipMemsetAsync(deg, 0, (size_t)NN * sizeof(int), stream);
  hipMemsetAsync(cursor, 0, (size_t)NN * sizeof(int), stream);

  prep_fcf<<<(NR * DIN * 144 + 255) / 256, 256, 0, stream>>>(fc, attn, fcf);

  gemm_mfma<<<(NN + 63) / 64, 256, 0, stream>>>(h, fcf, z, s_buf);

  hist_kernel<<<(NE + 255) / 256, 256, 0, stream>>>(dst, deg);
  scan1<<<NB_SCAN, 256, 0, stream>>>(deg, bsum);
  scan2<<<1, 256, 0, stream>>>(bsum, bbase, row_start);
  scan3<<<NB_SCAN, 256, 0, stream>>>(deg, bbase, row_start);

  scatter_kernel<<<(NE + 255) / 256, 256, 0, stream>>>(src, dst, et, s_buf,
                                                       row_start, cursor, es, sidx);

  node_accum<<<(NN + 3) / 4, 256, 0, stream>>>(row_start, es, sidx, z, out);
}

// Round 7
// 283.955 us; speedup vs baseline: 22.3238x; 1.0851x over previous
//
#include <hip/hip_runtime.h>

#define NN 50000
#define NE 800000
#define NR 8
#define DIN 128
#define DOUT 128
#define NH 8

#define NB_SCAN ((NN + 255) / 256)  // 196

typedef __attribute__((ext_vector_type(8))) short bf16x8;
typedef __attribute__((ext_vector_type(4))) float f32x4;

// ---------- helpers ----------
__device__ __forceinline__ unsigned short f2bf(float f) {
  unsigned u = __float_as_uint(f);
  unsigned r = (u + 0x7FFFu + ((u >> 16) & 1u)) >> 16;
  return (unsigned short)r;
}
__device__ __forceinline__ float bf2f(unsigned short b) {
  return __uint_as_float(((unsigned)b) << 16);
}

// ---------- prep: B-ext = [fc[r] | fc[r]@W2] in MFMA fragment order ----------
__global__ __launch_bounds__(256) void prep_fcf(
    const float* __restrict__ fc, const float* __restrict__ attn,
    unsigned short* __restrict__ fcf) {
  int idx = blockIdx.x * 256 + threadIdx.x;
  if (idx >= NR * DIN * 144) return;
  int r = idx / (DIN * 144);
  int rem = idx - r * (DIN * 144);
  int k = rem / 144;
  int j = rem - k * 144;
  float v;
  if (j < DOUT) {
    v = fc[((size_t)r * DIN + k) * DOUT + j];
  } else {
    int cc = j - DOUT;  // 0..15
    int hh = cc & 7, p = cc >> 3;
    const float* fr = fc + ((size_t)r * DIN + k) * DOUT + hh * 16;
    const float* ar = attn + ((size_t)r * NH + hh) * 32 + p * 16;
    v = 0.f;
#pragma unroll
    for (int d = 0; d < 16; ++d) v += fr[d] * ar[d];
  }
  int t = j >> 4, c = j & 15, ks = k >> 5, gg = (k >> 3) & 3, i = k & 7;
  fcf[((((size_t)r * 9 + t) * 4 + ks) * 4 + gg) * 128 + c * 8 + i] = f2bf(v);
}

// ---------- kernel 1: MFMA GEMM, 4 relations per block, LDS-staged z stores ----
__global__ __launch_bounds__(256) void gemm_mfma(
    const float* __restrict__ h, const unsigned short* __restrict__ fcf,
    unsigned short* __restrict__ z, unsigned short* __restrict__ s_buf) {
  const int n0 = blockIdx.x * 64;
  const int rr0 = blockIdx.y * 4;
  const int w = threadIdx.x >> 6;
  const int lane = threadIdx.x & 63;
  const int g = lane >> 4, c = lane & 15;
  const int nbase = n0 + w * 16;

  // 16 nodes x 130 shorts (pad 2) per wave
  __shared__ unsigned short zst[4][16][130];

  // A fragments: row = nbase + c, k = ks*32 + g*8 + i; fp32->bf16 in-kernel
  int arow = nbase + c;
  if (arow > NN - 1) arow = NN - 1;
  const float* ha = h + (size_t)arow * DIN + g * 8;
  bf16x8 af[4];
#pragma unroll
  for (int ks = 0; ks < 4; ++ks) {
    float4 v0 = *(const float4*)(ha + ks * 32);
    float4 v1 = *(const float4*)(ha + ks * 32 + 4);
    bf16x8 a;
    a[0] = (short)f2bf(v0.x); a[1] = (short)f2bf(v0.y);
    a[2] = (short)f2bf(v0.z); a[3] = (short)f2bf(v0.w);
    a[4] = (short)f2bf(v1.x); a[5] = (short)f2bf(v1.y);
    a[6] = (short)f2bf(v1.z); a[7] = (short)f2bf(v1.w);
    af[ks] = a;
  }

  const int node = nbase + c;

  for (int ri = 0; ri < 4; ++ri) {
    const int r = rr0 + ri;
    const unsigned short* fb = fcf + ((size_t)r * 36 * 64 + lane) * 8;
    f32x4 acc[9];
#pragma unroll
    for (int t = 0; t < 9; ++t) acc[t] = (f32x4){0.f, 0.f, 0.f, 0.f};

    // swapped operands: lane owns node col; rows = j-cols of output
#pragma unroll
    for (int ks = 0; ks < 4; ++ks)
#pragma unroll
      for (int t = 0; t < 9; ++t) {
        bf16x8 bf = *(const bf16x8*)(fb + (size_t)(t * 4 + ks) * 512);
        acc[t] = __builtin_amdgcn_mfma_f32_16x16x32_bf16(bf, af[ks], acc[t], 0, 0, 0);
      }

    // stage z-tile to LDS (lane owns node c, cols t*16+g*4..+3)
#pragma unroll
    for (int t = 0; t < 8; ++t) {
      ushort4 wv;
      wv.x = f2bf(acc[t][0]); wv.y = f2bf(acc[t][1]);
      wv.z = f2bf(acc[t][2]); wv.w = f2bf(acc[t][3]);
      *(ushort4*)&zst[w][c][t * 16 + g * 4] = wv;
    }
    __builtin_amdgcn_s_waitcnt(0);  // lgkmcnt(0): LDS writes visible to own wave
    // stream out coalesced: 4 x 1KB per wave, rows of 16 consecutive nodes
    unsigned short* zb = z + ((size_t)r * NN + nbase) * DOUT;
#pragma unroll
    for (int p = 0; p < 4; ++p) {
      int row = 4 * p + (lane >> 4);
      if (nbase + row < NN) {
        bf16x8 v = *(const bf16x8*)&zst[w][row][(lane & 15) * 8];
        *(bf16x8*)(zb + row * DOUT + (lane & 15) * 8) = v;
      }
    }

    if (node < NN) {
      ushort4 sv;
      sv.x = f2bf(acc[8][0]); sv.y = f2bf(acc[8][1]);
      sv.z = f2bf(acc[8][2]); sv.w = f2bf(acc[8][3]);
      *(ushort4*)&s_buf[((size_t)r * NN + node) * 16 + g * 4] = sv;
    }
  }
}

// ---------- kernel 2: degree histogram ----------
__global__ __launch_bounds__(256) void hist_kernel(const int* __restrict__ dst,
                                                   int* __restrict__ deg) {
  int e = blockIdx.x * blockDim.x + threadIdx.x;
  if (e < NE) atomicAdd(&deg[dst[e]], 1);
}

// ---------- kernel 3a: per-block sums of deg ----------
__global__ __launch_bounds__(256) void scan1(const int* __restrict__ deg,
                                             int* __restrict__ bsum) {
  __shared__ int ws_[4];
  int gi = blockIdx.x * 256 + threadIdx.x;
  int v = (gi < NN) ? deg[gi] : 0;
#pragma unroll
  for (int m = 1; m < 64; m <<= 1) v += __shfl_xor(v, m);
  if ((threadIdx.x & 63) == 0) ws_[threadIdx.x >> 6] = v;
  __syncthreads();
  if (threadIdx.x == 0) bsum[blockIdx.x] = ws_[0] + ws_[1] + ws_[2] + ws_[3];
}

// ---------- kernel 3b: scan the 196 block sums (1 block) ----------
__global__ __launch_bounds__(256) void scan2(const int* __restrict__ bsum,
                                             int* __restrict__ bbase,
                                             int* __restrict__ row_start) {
  __shared__ int part[256];
  int t = threadIdx.x;
  part[t] = (t < NB_SCAN) ? bsum[t] : 0;
  __syncthreads();
  for (int off = 1; off < 256; off <<= 1) {
    int v = (t >= off) ? part[t - off] : 0;
    __syncthreads();
    part[t] += v;
    __syncthreads();
  }
  if (t < NB_SCAN) bbase[t] = (t == 0) ? 0 : part[t - 1];
  if (t == 0) row_start[NN] = NE;
}

// ---------- kernel 3c: block-local scan + base -> row_start ----------
__global__ __launch_bounds__(256) void scan3(const int* __restrict__ deg,
                                             const int* __restrict__ bbase,
                                             int* __restrict__ row_start) {
  __shared__ int part[256];
  int t = threadIdx.x;
  int gi = blockIdx.x * 256 + t;
  int v = (gi < NN) ? deg[gi] : 0;
  part[t] = v;
  __syncthreads();
  for (int off = 1; off < 256; off <<= 1) {
    int x = (t >= off) ? part[t - off] : 0;
    __syncthreads();
    part[t] += x;
    __syncthreads();
  }
  if (gi < NN) row_start[gi] = bbase[blockIdx.x] + part[t] - v;
}

// ---------- kernel 4: scatter edges into CSR order, fold leaky-relu ----------
__global__ __launch_bounds__(256) void scatter_kernel(
    const int* __restrict__ src, const int* __restrict__ dst,
    const int* __restrict__ et, const unsigned short* __restrict__ s_buf,
    const int* __restrict__ row_start, int* __restrict__ cursor,
    unsigned short* __restrict__ es, unsigned* __restrict__ sidx) {
  int e = blockIdx.x * blockDim.x + threadIdx.x;
  if (e >= NE) return;
  int s = src[e], d = dst[e], r = et[e];
  int pos = row_start[d] + atomicAdd(&cursor[d], 1);
  ushort4 sa0 = *(const ushort4*)&s_buf[((size_t)r * NN + s) * 16];
  ushort4 sa1 = *(const ushort4*)&s_buf[((size_t)r * NN + s) * 16 + 4];
  ushort4 sb0 = *(const ushort4*)&s_buf[((size_t)r * NN + d) * 16 + 8];
  ushort4 sb1 = *(const ushort4*)&s_buf[((size_t)r * NN + d) * 16 + 12];
  float ev[8] = {bf2f(sa0.x) + bf2f(sb0.x), bf2f(sa0.y) + bf2f(sb0.y),
                 bf2f(sa0.z) + bf2f(sb0.z), bf2f(sa0.w) + bf2f(sb0.w),
                 bf2f(sa1.x) + bf2f(sb1.x), bf2f(sa1.y) + bf2f(sb1.y),
                 bf2f(sa1.z) + bf2f(sb1.z), bf2f(sa1.w) + bf2f(sb1.w)};
  ushort4 w0, w1;
  unsigned short wv[8];
#pragma unroll
  for (int hh = 0; hh < 8; ++hh) {
    float x = ev[hh];
    x = x > 0.f ? x : 0.01f * x;
    wv[hh] = f2bf(x);
  }
  w0.x = wv[0]; w0.y = wv[1]; w0.z = wv[2]; w0.w = wv[3];
  w1.x = wv[4]; w1.y = wv[5]; w1.z = wv[6]; w1.w = wv[7];
  *(ushort4*)&es[(size_t)pos * 8] = w0;
  *(ushort4*)&es[(size_t)pos * 8 + 4] = w1;
  sidx[pos] = (unsigned)s | ((unsigned)r << 16);
}

// ---------- kernel 5: per-node softmax + weighted gather (1 wave/node) ----------
__global__ __launch_bounds__(256) void node_accum(
    const int* __restrict__ row_start, const unsigned short* __restrict__ es,
    const unsigned* __restrict__ sidx, const unsigned short* __restrict__ z,
    float* __restrict__ out) {
  int wave = threadIdx.x >> 6;
  int lane = threadIdx.x & 63;
  int n = blockIdx.x * 4 + wave;
  if (n >= NN) return;
  int b0 = row_start[n];
  int deg = row_start[n + 1] - b0;

  int hl = lane & 7;   // head this lane scores
  int jg = lane >> 3;  // edge slot within chunk of 8 (score pass)
  int c16 = lane & 15; // col-block owner (8 elems at c16*8)
  int e4 = lane >> 4;  // edge-within-4-group this lane gathers

  float maxv = -INFINITY;
  for (int j = jg; j < deg; j += 8)
    maxv = fmaxf(maxv, bf2f(es[(size_t)(b0 + j) * 8 + hl]));
#pragma unroll
  for (int m = 8; m < 64; m <<= 1) maxv = fmaxf(maxv, __shfl_xor(maxv, m));

  float acc[8] = {0.f, 0.f, 0.f, 0.f, 0.f, 0.f, 0.f, 0.f};
  float den = 0.f;
  int hh16 = c16 >> 1;  // head of this lane's 8 output elems

  for (int cch = 0; cch < deg; cch += 8) {
    int j = cch + jg;
    float ex = 0.f;
    if (j < deg) ex = __expf(bf2f(es[(size_t)(b0 + j) * 8 + hl]) - maxv);
    den += ex;
    int rem = min(8, deg - cch);
    unsigned pk = sidx[b0 + cch + min(lane & 7, rem - 1)];
#pragma unroll
    for (int half = 0; half < 2; ++half) {
      if (half * 4 >= rem) break;
      int o = half * 4 + e4;
      float exb = __shfl(ex, (o << 3) | hh16);
      unsigned p = __shfl(pk, o);
      unsigned sr_ = p & 0xFFFFu;
      unsigned rr = p >> 16;
      bf16x8 v = *(const bf16x8*)&z[(((size_t)rr * NN + sr_) << 7) + c16 * 8];
#pragma unroll
      for (int i = 0; i < 8; ++i)
        acc[i] += exb * bf2f((unsigned short)v[i]);
    }
  }
#pragma unroll
  for (int m = 8; m < 64; m <<= 1) den += __shfl_xor(den, m);
#pragma unroll
  for (int i = 0; i < 8; ++i) {
    acc[i] += __shfl_xor(acc[i], 16);
    acc[i] += __shfl_xor(acc[i], 32);
  }
  float deno = __shfl(den, hh16);
  float inv = 1.0f / fmaxf(deno, 1e-9f);
  if (lane < 16) {
    float* ob = out + ((size_t)n << 7) + lane * 8;
    *(float4*)ob = make_float4(acc[0] * inv, acc[1] * inv, acc[2] * inv, acc[3] * inv);
    *(float4*)(ob + 4) = make_float4(acc[4] * inv, acc[5] * inv, acc[6] * inv, acc[7] * inv);
  }
}

extern "C" void kernel_launch(void* const* d_in, const int* in_sizes, int n_in,
                              void* d_out, int out_size, void* d_ws, size_t ws_size,
                              hipStream_t stream) {
  const float* h = (const float*)d_in[0];
  const float* fc = (const float*)d_in[1];
  const float* attn = (const float*)d_in[2];
  const int* src = (const int*)d_in[3];
  const int* dst = (const int*)d_in[4];
  const int* et = (const int*)d_in[5];
  float* out = (float*)d_out;

  // workspace layout (16B-aligned chunks first)
  char* wsb = (char*)d_ws;
  size_t off = 0;
  unsigned short* z = (unsigned short*)(wsb + off);    off += (size_t)NR * NN * DOUT * 2;      // 102.4 MB
  unsigned short* s_buf = (unsigned short*)(wsb + off);off += (size_t)NR * NN * 16 * 2;        // 12.8 MB
  unsigned short* es = (unsigned short*)(wsb + off);   off += (size_t)NE * NH * 2;             // 12.8 MB
  unsigned* sidx = (unsigned*)(wsb + off);             off += (size_t)NE * 4;                  // 3.2 MB
  unsigned short* fcf = (unsigned short*)(wsb + off);  off += (size_t)NR * 9 * 4 * 4 * 128 * 2;// 0.3 MB
  int* deg = (int*)(wsb + off);                        off += (size_t)NN * 4;
  int* row_start = (int*)(wsb + off);                  off += (size_t)(NN + 1) * 4;
  int* cursor = (int*)(wsb + off);                     off += (size_t)NN * 4;
  int* bsum = (int*)(wsb + off);                       off += (size_t)NB_SCAN * 4;
  int* bbase = (int*)(wsb + off);                      off += (size_t)NB_SCAN * 4;

  hipMemsetAsync(deg, 0, (size_t)NN * sizeof(int), stream);
  hipMemsetAsync(cursor, 0, (size_t)NN * sizeof(int), stream);

  prep_fcf<<<(NR * DIN * 144 + 255) / 256, 256, 0, stream>>>(fc, attn, fcf);

  dim3 ggrid((NN + 63) / 64, 2);
  gemm_mfma<<<ggrid, 256, 0, stream>>>(h, fcf, z, s_buf);

  hist_kernel<<<(NE + 255) / 256, 256, 0, stream>>>(dst, deg);
  scan1<<<NB_SCAN, 256, 0, stream>>>(deg, bsum);
  scan2<<<1, 256, 0, stream>>>(bsum, bbase, row_start);
  scan3<<<NB_SCAN, 256, 0, stream>>>(deg, bbase, row_start);

  scatter_kernel<<<(NE + 255) / 256, 256, 0, stream>>>(src, dst, et, s_buf,
                                                       row_start, cursor, es, sidx);

  node_accum<<<(NN + 3) / 4, 256, 0, stream>>>(row_start, es, sidx, z, out);
}

// Round 8
// 274.503 us; speedup vs baseline: 23.0926x; 1.0344x over previous
//
#include <hip/hip_runtime.h>

#define NN 50000
#define NE 800000
#define NR 8
#define DIN 128
#define DOUT 128
#define NH 8

#define NB_SCAN ((NN + 255) / 256)  // 196

typedef __attribute__((ext_vector_type(8))) short bf16x8;
typedef __attribute__((ext_vector_type(4))) float f32x4;

// ---------- helpers ----------
__device__ __forceinline__ unsigned short f2bf(float f) {
  unsigned u = __float_as_uint(f);
  unsigned r = (u + 0x7FFFu + ((u >> 16) & 1u)) >> 16;
  return (unsigned short)r;
}
__device__ __forceinline__ float bf2f(unsigned short b) {
  return __uint_as_float(((unsigned)b) << 16);
}

// ---------- prep: B-ext = [fc[r] | fc[r]@W2] in MFMA fragment order ----------
__global__ __launch_bounds__(256) void prep_fcf(
    const float* __restrict__ fc, const float* __restrict__ attn,
    unsigned short* __restrict__ fcf) {
  int idx = blockIdx.x * 256 + threadIdx.x;
  if (idx >= NR * DIN * 144) return;
  int r = idx / (DIN * 144);
  int rem = idx - r * (DIN * 144);
  int k = rem / 144;
  int j = rem - k * 144;
  float v;
  if (j < DOUT) {
    v = fc[((size_t)r * DIN + k) * DOUT + j];
  } else {
    int cc = j - DOUT;  // 0..15
    int hh = cc & 7, p = cc >> 3;
    const float* fr = fc + ((size_t)r * DIN + k) * DOUT + hh * 16;
    const float* ar = attn + ((size_t)r * NH + hh) * 32 + p * 16;
    v = 0.f;
#pragma unroll
    for (int d = 0; d < 16; ++d) v += fr[d] * ar[d];
  }
  int t = j >> 4, c = j & 15, ks = k >> 5, gg = (k >> 3) & 3, i = k & 7;
  fcf[((((size_t)r * 9 + t) * 4 + ks) * 4 + gg) * 128 + c * 8 + i] = f2bf(v);
}

// ---------- kernel 1: MFMA GEMM, 4 relations per block, LDS-staged z stores ----
__global__ __launch_bounds__(256) void gemm_mfma(
    const float* __restrict__ h, const unsigned short* __restrict__ fcf,
    unsigned short* __restrict__ z, unsigned short* __restrict__ s_buf) {
  const int n0 = blockIdx.x * 64;
  const int rr0 = blockIdx.y * 4;
  const int w = threadIdx.x >> 6;
  const int lane = threadIdx.x & 63;
  const int g = lane >> 4, c = lane & 15;
  const int nbase = n0 + w * 16;

  __shared__ unsigned short zst[4][16][130];

  int arow = nbase + c;
  if (arow > NN - 1) arow = NN - 1;
  const float* ha = h + (size_t)arow * DIN + g * 8;
  bf16x8 af[4];
#pragma unroll
  for (int ks = 0; ks < 4; ++ks) {
    float4 v0 = *(const float4*)(ha + ks * 32);
    float4 v1 = *(const float4*)(ha + ks * 32 + 4);
    bf16x8 a;
    a[0] = (short)f2bf(v0.x); a[1] = (short)f2bf(v0.y);
    a[2] = (short)f2bf(v0.z); a[3] = (short)f2bf(v0.w);
    a[4] = (short)f2bf(v1.x); a[5] = (short)f2bf(v1.y);
    a[6] = (short)f2bf(v1.z); a[7] = (short)f2bf(v1.w);
    af[ks] = a;
  }

  const int node = nbase + c;

  for (int ri = 0; ri < 4; ++ri) {
    const int r = rr0 + ri;
    const unsigned short* fb = fcf + ((size_t)r * 36 * 64 + lane) * 8;
    f32x4 acc[9];
#pragma unroll
    for (int t = 0; t < 9; ++t) acc[t] = (f32x4){0.f, 0.f, 0.f, 0.f};

#pragma unroll
    for (int ks = 0; ks < 4; ++ks)
#pragma unroll
      for (int t = 0; t < 9; ++t) {
        bf16x8 bf = *(const bf16x8*)(fb + (size_t)(t * 4 + ks) * 512);
        acc[t] = __builtin_amdgcn_mfma_f32_16x16x32_bf16(bf, af[ks], acc[t], 0, 0, 0);
      }

#pragma unroll
    for (int t = 0; t < 8; ++t) {
      ushort4 wv;
      wv.x = f2bf(acc[t][0]); wv.y = f2bf(acc[t][1]);
      wv.z = f2bf(acc[t][2]); wv.w = f2bf(acc[t][3]);
      *(ushort4*)&zst[w][c][t * 16 + g * 4] = wv;
    }
    __builtin_amdgcn_s_waitcnt(0);  // lgkmcnt(0)
    unsigned short* zb = z + ((size_t)r * NN + nbase) * DOUT;
#pragma unroll
    for (int p = 0; p < 4; ++p) {
      int row = 4 * p + (lane >> 4);
      if (nbase + row < NN) {
        bf16x8 v = *(const bf16x8*)&zst[w][row][(lane & 15) * 8];
        *(bf16x8*)(zb + row * DOUT + (lane & 15) * 8) = v;
      }
    }

    if (node < NN) {
      ushort4 sv;
      sv.x = f2bf(acc[8][0]); sv.y = f2bf(acc[8][1]);
      sv.z = f2bf(acc[8][2]); sv.w = f2bf(acc[8][3]);
      *(ushort4*)&s_buf[((size_t)r * NN + node) * 16 + g * 4] = sv;
    }
  }
}

// ---------- kernel 2: degree histogram ----------
__global__ __launch_bounds__(256) void hist_kernel(const int* __restrict__ dst,
                                                   int* __restrict__ deg) {
  int e = blockIdx.x * blockDim.x + threadIdx.x;
  if (e < NE) atomicAdd(&deg[dst[e]], 1);
}

// ---------- kernel 3a: per-block sums of deg ----------
__global__ __launch_bounds__(256) void scan1(const int* __restrict__ deg,
                                             int* __restrict__ bsum) {
  __shared__ int ws_[4];
  int gi = blockIdx.x * 256 + threadIdx.x;
  int v = (gi < NN) ? deg[gi] : 0;
#pragma unroll
  for (int m = 1; m < 64; m <<= 1) v += __shfl_xor(v, m);
  if ((threadIdx.x & 63) == 0) ws_[threadIdx.x >> 6] = v;
  __syncthreads();
  if (threadIdx.x == 0) bsum[blockIdx.x] = ws_[0] + ws_[1] + ws_[2] + ws_[3];
}

// ---------- kernel 3b: scan the 196 block sums (1 block) ----------
__global__ __launch_bounds__(256) void scan2(const int* __restrict__ bsum,
                                             int* __restrict__ bbase,
                                             int* __restrict__ row_start) {
  __shared__ int part[256];
  int t = threadIdx.x;
  part[t] = (t < NB_SCAN) ? bsum[t] : 0;
  __syncthreads();
  for (int off = 1; off < 256; off <<= 1) {
    int v = (t >= off) ? part[t - off] : 0;
    __syncthreads();
    part[t] += v;
    __syncthreads();
  }
  if (t < NB_SCAN) bbase[t] = (t == 0) ? 0 : part[t - 1];
  if (t == 0) row_start[NN] = NE;
}

// ---------- kernel 3c: block-local scan + base -> row_start ----------
__global__ __launch_bounds__(256) void scan3(const int* __restrict__ deg,
                                             const int* __restrict__ bbase,
                                             int* __restrict__ row_start) {
  __shared__ int part[256];
  int t = threadIdx.x;
  int gi = blockIdx.x * 256 + t;
  int v = (gi < NN) ? deg[gi] : 0;
  part[t] = v;
  __syncthreads();
  for (int off = 1; off < 256; off <<= 1) {
    int x = (t >= off) ? part[t - off] : 0;
    __syncthreads();
    part[t] += x;
    __syncthreads();
  }
  if (gi < NN) row_start[gi] = bbase[blockIdx.x] + part[t] - v;
}

// ---------- kernel 4: scatter CSR permutation only (4 B/edge) ----------
__global__ __launch_bounds__(256) void scatter_kernel(
    const int* __restrict__ src, const int* __restrict__ dst,
    const int* __restrict__ et, const int* __restrict__ row_start,
    int* __restrict__ cursor, unsigned* __restrict__ sidx) {
  int e = blockIdx.x * blockDim.x + threadIdx.x;
  if (e >= NE) return;
  int d = dst[e];
  int pos = row_start[d] + atomicAdd(&cursor[d], 1);
  sidx[pos] = (unsigned)src[e] | ((unsigned)et[e] << 16);
}

// ---------- kernel 5: online-softmax gather-accumulate (1 wave/node) ----------
__global__ __launch_bounds__(256) void node_accum(
    const int* __restrict__ row_start, const unsigned* __restrict__ sidx,
    const unsigned short* __restrict__ s_buf, const unsigned short* __restrict__ z,
    float* __restrict__ out) {
  int wave = threadIdx.x >> 6;
  int lane = threadIdx.x & 63;
  int n = blockIdx.x * 4 + wave;
  if (n >= NN) return;
  int b0 = row_start[n];
  int deg = row_start[n + 1] - b0;

  int hl = lane & 7;    // head for score lanes
  int jg = lane >> 3;   // edge slot (0..7)
  int c16 = lane & 15;  // output col-block
  int e4 = lane >> 4;   // edge-subgroup for gather
  int hh16 = c16 >> 1;  // head of this lane's output cols

  // preload dst-half scores for all 8 relations (this node, head hl)
  float srn[8];
#pragma unroll
  for (int r = 0; r < 8; ++r)
    srn[r] = bf2f(s_buf[((size_t)r * NN + n) * 16 + 8 + hl]);

  float m = -INFINITY;  // running per-head max (replicated across jg lanes)
  float den = 0.f;
  float acc[8] = {0.f, 0.f, 0.f, 0.f, 0.f, 0.f, 0.f, 0.f};

  for (int cch = 0; cch < deg; cch += 8) {
    int j = cch + jg;
    int rem = min(8, deg - cch);
    // score for (edge j, head hl)
    float ev = -INFINITY;
    unsigned pj = 0;
    if (j < deg) {
      pj = sidx[b0 + j];
      unsigned s = pj & 0xFFFFu, r = pj >> 16;
      float sl = bf2f(s_buf[((size_t)r * NN + s) * 16 + hl]);
      float x = sl + srn[r];
      ev = x > 0.f ? x : 0.01f * x;
    }
    // chunk max over edge-slot axis
    float cm = ev;
    cm = fmaxf(cm, __shfl_xor(cm, 8));
    cm = fmaxf(cm, __shfl_xor(cm, 16));
    cm = fmaxf(cm, __shfl_xor(cm, 32));
    float newm = fmaxf(m, cm);
    float scale = __expf(m - newm);  // m=-inf first chunk -> 0
    float ex = __expf(ev - newm);    // ev=-inf -> 0
    float sumex = ex;
    sumex += __shfl_xor(sumex, 8);
    sumex += __shfl_xor(sumex, 16);
    sumex += __shfl_xor(sumex, 32);
    den = den * scale + sumex;
    m = newm;
    // rescale acc (per this lane's output head)
    float sc_acc = __shfl(scale, hh16);
#pragma unroll
    for (int i = 0; i < 8; ++i) acc[i] *= sc_acc;
    // z accumulate: 4 edges per half, 16B/lane gathers
#pragma unroll
    for (int half = 0; half < 2; ++half) {
      if (half * 4 >= rem) break;
      int o = half * 4 + e4;
      float exb = __shfl(ex, (o << 3) | hh16);  // 0 for o >= rem
      unsigned p = __shfl(pj, o << 3);          // 0 for o >= rem -> z row 0, x0
      unsigned sr_ = p & 0xFFFFu;
      unsigned rr = p >> 16;
      bf16x8 v = *(const bf16x8*)&z[(((size_t)rr * NN + sr_) << 7) + c16 * 8];
#pragma unroll
      for (int i = 0; i < 8; ++i)
        acc[i] += exb * bf2f((unsigned short)v[i]);
    }
  }
  // merge the 4 edge-subgroups
#pragma unroll
  for (int i = 0; i < 8; ++i) {
    acc[i] += __shfl_xor(acc[i], 16);
    acc[i] += __shfl_xor(acc[i], 32);
  }
  float deno = __shfl(den, hh16);
  float inv = 1.0f / fmaxf(deno, 1e-9f);
  if (lane < 16) {
    float* ob = out + ((size_t)n << 7) + lane * 8;
    *(float4*)ob = make_float4(acc[0] * inv, acc[1] * inv, acc[2] * inv, acc[3] * inv);
    *(float4*)(ob + 4) = make_float4(acc[4] * inv, acc[5] * inv, acc[6] * inv, acc[7] * inv);
  }
}

extern "C" void kernel_launch(void* const* d_in, const int* in_sizes, int n_in,
                              void* d_out, int out_size, void* d_ws, size_t ws_size,
                              hipStream_t stream) {
  const float* h = (const float*)d_in[0];
  const float* fc = (const float*)d_in[1];
  const float* attn = (const float*)d_in[2];
  const int* src = (const int*)d_in[3];
  const int* dst = (const int*)d_in[4];
  const int* et = (const int*)d_in[5];
  float* out = (float*)d_out;

  // workspace layout (16B-aligned chunks first)
  char* wsb = (char*)d_ws;
  size_t off = 0;
  unsigned short* z = (unsigned short*)(wsb + off);    off += (size_t)NR * NN * DOUT * 2;      // 102.4 MB
  unsigned short* s_buf = (unsigned short*)(wsb + off);off += (size_t)NR * NN * 16 * 2;        // 12.8 MB
  unsigned* sidx = (unsigned*)(wsb + off);             off += (size_t)NE * 4;                  // 3.2 MB
  unsigned short* fcf = (unsigned short*)(wsb + off);  off += (size_t)NR * 9 * 4 * 4 * 128 * 2;// 0.3 MB
  int* deg = (int*)(wsb + off);                        off += (size_t)NN * 4;
  int* row_start = (int*)(wsb + off);                  off += (size_t)(NN + 1) * 4;
  int* cursor = (int*)(wsb + off);                     off += (size_t)NN * 4;
  int* bsum = (int*)(wsb + off);                       off += (size_t)NB_SCAN * 4;
  int* bbase = (int*)(wsb + off);                      off += (size_t)NB_SCAN * 4;

  hipMemsetAsync(deg, 0, (size_t)NN * sizeof(int), stream);
  hipMemsetAsync(cursor, 0, (size_t)NN * sizeof(int), stream);

  prep_fcf<<<(NR * DIN * 144 + 255) / 256, 256, 0, stream>>>(fc, attn, fcf);

  dim3 ggrid((NN + 63) / 64, 2);
  gemm_mfma<<<ggrid, 256, 0, stream>>>(h, fcf, z, s_buf);

  hist_kernel<<<(NE + 255) / 256, 256, 0, stream>>>(dst, deg);
  scan1<<<NB_SCAN, 256, 0, stream>>>(deg, bsum);
  scan2<<<1, 256, 0, stream>>>(bsum, bbase, row_start);
  scan3<<<NB_SCAN, 256, 0, stream>>>(deg, bbase, row_start);

  scatter_kernel<<<(NE + 255) / 256, 256, 0, stream>>>(src, dst, et, row_start,
                                                       cursor, sidx);

  node_accum<<<(NN + 3) / 4, 256, 0, stream>>>(row_start, sidx, s_buf, z, out);
}